// Round 10
// baseline (3678.754 us; speedup 1.0000x reference)
//
#include <hip/hip_runtime.h>
#include <hip/hip_cooperative_groups.h>
#include <math.h>
namespace cg = cooperative_groups;

#define NB 4
#define NW 24
#define H 512
#define H2 1024
#define H5 2560
#define NCELL 300   // n*(n+1)/2 valid cells per batch
#define NBLK 480    // 96 j-groups x 5; <=2 blocks/CU -> co-resident for cooperative launch

// workspace floats: WbilT + chartH + chartC + chartS + PI + PS + U
#define NEED_FLOATS ((size_t)H2*H2 + 2u*NB*NCELL*H + NB*NCELL + 2u*NB*NCELL*H5 + NB*NCELL*H2)
#define NEED_BYTES  ((size_t)NEED_FLOATS * 4u)

// Private fallback workspace: allocated ONCE at library load (outside
// kernel_launch, so graph capture never sees the hipMalloc). d_ws proved too
// small in round 1 (44.9MB layout corrupted adjacent harness allocations).
static float* g_buf = nullptr;
__attribute__((constructor)) static void dio_alloc_ws(){
  (void)hipMalloc((void**)&g_buf, NEED_BYTES + (1u<<20));
}

__device__ __forceinline__ int coff(int l){ return l*NW - (l*(l-1))/2; }
__device__ __forceinline__ float sigm(float x){ return 1.f/(1.f+__expf(-x)); }
__device__ __forceinline__ float ftanh(float x){ return 1.f - 2.f/(__expf(2.f*x)+1.f); }

// One persistent cooperative kernel for the whole inside-pass.
// Round-9 lesson: each of the 46 dispatches re-fetched the full 14.6MB weight
// set (FETCH ~8.7MB/dispatch) because kernel boundaries flush caches; grid.sync
// keeps blocks resident and each block's fixed j-group slice warm in L2.
__global__ void __launch_bounds__(256, 2)
k_fused(const float* __restrict__ seqt, const float* __restrict__ Wi,
        const float* __restrict__ bi, const float* __restrict__ Ws,
        const float* __restrict__ bs, const float* __restrict__ Wbil,
        float* __restrict__ WbilT,
        float* __restrict__ cH, float* __restrict__ cC, float* __restrict__ cS,
        float* __restrict__ cPI, float* __restrict__ cPS, float* __restrict__ cU,
        float* __restrict__ out)
{
  cg::grid_group grid = cg::this_grid();
  __shared__ float As[8*512];        // proj A-tile / transpose scratch (16 KB)
  __shared__ float compat_s[32];
  __shared__ float wts_s[32];
  __shared__ float S_s;
  const int t   = threadIdx.x;
  const int blk = blockIdx.x;
  const int wave = t>>6, lane = t&63;
  const int jj = lane & 15, kk = lane >> 4;

  // ---- P0: transpose Wbil -> WbilT (k-contiguous for U), leaf init
  {
    float (*tile)[33] = (float(*)[33])As;
    const int tx = t & 31, ty = t >> 5;   // 32 x 8
    for (int tt = blk; tt < 1024; tt += NBLK){
      int tr = (tt >> 5) * 32, tc = (tt & 31) * 32;
      __syncthreads();
      #pragma unroll
      for (int i=0;i<32;i+=8)
        tile[ty+i][tx] = Wbil[(size_t)(tr+ty+i)*H2 + tc+tx];
      __syncthreads();
      #pragma unroll
      for (int i=0;i<32;i+=8)
        WbilT[(size_t)(tc+ty+i)*H2 + tr+tx] = tile[tx][ty+i];
    }
    int tid = blk*256 + t;
    if (tid < NB*NW*H){
      int b = tid/(NW*H); int r = tid%(NW*H); int i = r/H; int dd = r%H;
      int cell = b*NCELL + i;               // coff(0)==0
      cH[(size_t)cell*H + dd] = seqt[(size_t)(b*NW+i)*H2 + dd];
      cC[(size_t)cell*H + dd] = seqt[(size_t)(b*NW+i)*H2 + H + dd];
      if (dd==0) cS[cell] = 0.f;
    }
  }
  grid.sync();

  // fixed j-group per block -> same weight slice every diagonal (L2-warm)
  const int jg  = blk / 5;     // 0..95
  const int sub = blk % 5;
  int kind, j0;
  if (jg < 40){ kind=0; j0 = jg*64; }
  else if (jg < 80){ kind=1; j0 = (jg-40)*64; }
  else { kind=2; j0 = (jg-80)*64; }
  const int j = j0 + wave*16 + jj;

  for (int L = 0; L < NW; L++){
    // ---- combine(L): one virtual block per (b,left) cell
    if (L >= 1){
      const int P = NW - L;
      for (int cellid = blk; cellid < NB*P; cellid += NBLK){
        const int b = cellid / P, left = cellid % P;
        for (int k=wave; k<L; k+=4){
          int lc = b*NCELL + coff(k) + left;
          int rc = b*NCELL + coff(L-1-k) + left+k+1;
          const float* U  = cU + (size_t)lc*H2;
          const float* Hr = cH + (size_t)rc*H;
          const float* Cr = cC + (size_t)rc*H;
          float p = 0.f;
          for (int i=lane; i<H; i+=64)
            p += U[i]*Hr[i] + U[H+i]*Cr[i];
          #pragma unroll
          for (int off=32; off>0; off>>=1) p += __shfl_down(p, off);
          if (lane==0) compat_s[k] = p + cS[lc] + cS[rc];
        }
        __syncthreads();
        if (t==0){
          float mx = -1e30f;
          for (int k=0;k<L;k++) mx = fmaxf(mx, compat_s[k]);
          float den = 0.f;
          for (int k=0;k<L;k++){ float e = __expf(compat_s[k]-mx); wts_s[k]=e; den+=e; }
          float inv = 1.f/den, S = 0.f;
          for (int k=0;k<L;k++){ wts_s[k]*=inv; S += wts_s[k]*compat_s[k]; }
          S_s = S;
        }
        __syncthreads();
        float aH0=0.f, aH1=0.f, aC0=0.f, aC1=0.f;
        const int d0 = t, d1 = t+256;
        for (int k=0;k<L;k++){
          float wk = wts_s[k];
          int lc = b*NCELL + coff(k) + left;
          int rc = b*NCELL + coff(L-1-k) + left+k+1;
          const float* PI  = cPI + (size_t)lc*H5;
          const float* PS  = cPS + (size_t)rc*H5;
          const float* lCp = cC + (size_t)lc*H;
          const float* rCp = cC + (size_t)rc*H;
          {
            float p0 = PI[d0]     + PS[d0];
            float p1 = PI[H+d0]   + PS[H+d0];
            float p2 = PI[2*H+d0] + PS[2*H+d0];
            float p3 = PI[3*H+d0] + PS[3*H+d0];
            float p4 = PI[4*H+d0] + PS[4*H+d0];
            float mem = sigm(p1)*lCp[d0] + sigm(p2)*rCp[d0] + sigm(p0)*ftanh(p3);
            float h = sigm(p4)*ftanh(mem);
            aH0 += wk*h; aC0 += wk*mem;
          }
          {
            float p0 = PI[d1]     + PS[d1];
            float p1 = PI[H+d1]   + PS[H+d1];
            float p2 = PI[2*H+d1] + PS[2*H+d1];
            float p3 = PI[3*H+d1] + PS[3*H+d1];
            float p4 = PI[4*H+d1] + PS[4*H+d1];
            float mem = sigm(p1)*lCp[d1] + sigm(p2)*rCp[d1] + sigm(p0)*ftanh(p3);
            float h = sigm(p4)*ftanh(mem);
            aH1 += wk*h; aC1 += wk*mem;
          }
        }
        int nc = b*NCELL + coff(L) + left;
        cH[(size_t)nc*H + d0] = aH0; cH[(size_t)nc*H + d1] = aH1;
        cC[(size_t)nc*H + d0] = aC0; cC[(size_t)nc*H + d1] = aC1;
        if (t==0) cS[nc] = S_s;
      }
      grid.sync();
    }

    // ---- proj(L): PI/PS/U for the cells just produced on diagonal L
    if (L < NW-1){
      const int P = NW - L;
      const int Mtot = NB*P;
      const int nmt = (Mtot+7)/8;
      for (int mt = sub; mt < nmt; mt += 5){
        const int m0 = mt*8;
        const int nm = min(8, Mtot-m0);
        int cells[8];
        #pragma unroll
        for (int m=0;m<8;m++){
          int mg = m0 + (m < nm ? m : 0);
          int b = mg/P, i = mg%P;
          cells[m] = b*NCELL + coff(L) + i;
        }
        float acc[8];
        #pragma unroll
        for (int m=0;m<8;m++) acc[m] = 0.f;

        const int npass = (kind==2) ? 2 : 1;
        for (int pass=0; pass<npass; pass++){
          const float* __restrict__ srcbase = (kind==2 && pass==1) ? cC : cH;
          __syncthreads();   // protect As reuse
          #pragma unroll
          for (int it=0; it<4; it++){
            int idx = t + it*256;
            int m = idx>>7, k4 = idx&127;
            ((float4*)As)[idx] = ((const float4*)(srcbase + (size_t)cells[m]*H))[k4];
          }
          __syncthreads();

          const float* __restrict__ gk;
          if (kind==0)      gk = Wi    + (size_t)j*H  + kk*4;
          else if (kind==1) gk = Ws    + (size_t)j*H  + kk*4;
          else              gk = WbilT + (size_t)j*H2 + (size_t)pass*H + kk*4;

          // 4 independent dwordx4 loads per iteration (in-iteration MLP=4)
          for (int c=0; c<32; c+=4){
            float4 wa = *(const float4*)(gk + (size_t)(c+0)*16);
            float4 wb = *(const float4*)(gk + (size_t)(c+1)*16);
            float4 wcv= *(const float4*)(gk + (size_t)(c+2)*16);
            float4 wd = *(const float4*)(gk + (size_t)(c+3)*16);
            #pragma unroll
            for (int q=0;q<4;q++){
              float4 w = (q==0)?wa:(q==1)?wb:(q==2)?wcv:wd;
              const int kb = (c+q)*16 + kk*4;
              #pragma unroll
              for (int m=0;m<8;m++){
                float4 a = *(const float4*)&As[m*512 + kb];
                acc[m] = fmaf(a.x, w.x, acc[m]);
                acc[m] = fmaf(a.y, w.y, acc[m]);
                acc[m] = fmaf(a.z, w.z, acc[m]);
                acc[m] = fmaf(a.w, w.w, acc[m]);
              }
            }
          }
        }

        // fold 4-way k-split (lanes differing in bits 4,5)
        #pragma unroll
        for (int m=0;m<8;m++){
          acc[m] += __shfl_xor(acc[m], 16);
          acc[m] += __shfl_xor(acc[m], 32);
        }
        if (kk == 0){
          float bias = 0.f;
          if (kind==0) bias = bi[j] + ((j>=H && j<3*H)?1.f:0.f);   // ins_bias on [H,3H)
          else if (kind==1) bias = bs[j];
          for (int m=0;m<nm;m++){
            int cell = cells[m];
            if (kind==0)      cPI[(size_t)cell*H5 + j] = acc[m]+bias;
            else if (kind==1) cPS[(size_t)cell*H5 + j] = acc[m]+bias;
            else              cU [(size_t)cell*H2 + j] = acc[m];
          }
        }
      }
      grid.sync();
    }
  }

  // ---- root output: concat(H, C) of cell (0, n-1)
  {
    int tid = blk*256 + t;
    if (tid < NB*H2){
      int b = tid>>10, dd = tid&1023;
      int cell = b*NCELL + 299;   // coff(23)+0
      out[tid] = (dd<H) ? cH[(size_t)cell*H + dd] : cC[(size_t)cell*H + (dd-H)];
    }
  }
}

extern "C" void kernel_launch(void* const* d_in, const int* in_sizes, int n_in,
                              void* d_out, int out_size, void* d_ws, size_t ws_size,
                              hipStream_t stream){
  const float* seqt = (const float*)d_in[0];
  const float* Wi   = (const float*)d_in[1];
  const float* bi   = (const float*)d_in[2];
  const float* Ws   = (const float*)d_in[3];
  const float* bs   = (const float*)d_in[4];
  const float* Wbil = (const float*)d_in[5];
  float* out = (float*)d_out;

  float* p = (ws_size >= NEED_BYTES && g_buf == nullptr) ? (float*)d_ws : g_buf;
  float* WbilT = p; p += (size_t)H2*H2;
  float* cH  = p; p += (size_t)NB*NCELL*H;
  float* cC  = p; p += (size_t)NB*NCELL*H;
  float* cS  = p; p += (size_t)NB*NCELL;
  float* cPI = p; p += (size_t)NB*NCELL*H5;
  float* cPS = p; p += (size_t)NB*NCELL*H5;
  float* cU  = p; p += (size_t)NB*NCELL*H2;

  void* args[] = { (void*)&seqt, (void*)&Wi, (void*)&bi, (void*)&Ws, (void*)&bs,
                   (void*)&Wbil, (void*)&WbilT, (void*)&cH, (void*)&cC, (void*)&cS,
                   (void*)&cPI, (void*)&cPS, (void*)&cU, (void*)&out };
  (void)hipLaunchCooperativeKernel((const void*)k_fused, dim3(NBLK), dim3(256),
                                   args, 0, stream);
}

// Round 11
// 1304.562 us; speedup vs baseline: 2.8199x; 2.8199x over previous
//
#include <hip/hip_runtime.h>
#include <math.h>

#define NB 4
#define NW 24
#define H 512
#define H2 1024
#define H5 2560
#define NCELL 300   // n*(n+1)/2 valid cells per batch

// workspace floats: WbilT + chartH + chartC + chartS + PI + PS + U
#define NEED_FLOATS ((size_t)H2*H2 + 2u*NB*NCELL*H + NB*NCELL + 2u*NB*NCELL*H5 + NB*NCELL*H2)
#define NEED_BYTES  ((size_t)NEED_FLOATS * 4u)

// Private fallback workspace: allocated ONCE at library load (outside
// kernel_launch, so graph capture never sees the hipMalloc). d_ws proved too
// small in round 1 (44.9MB layout corrupted adjacent harness allocations).
static float* g_buf = nullptr;
__attribute__((constructor)) static void dio_alloc_ws(){
  (void)hipMalloc((void**)&g_buf, NEED_BYTES + (1u<<20));
}

__device__ __forceinline__ int coff(int l){ return l*NW - (l*(l-1))/2; }
__device__ __forceinline__ float sigm(float x){ return 1.f/(1.f+__expf(-x)); }
__device__ __forceinline__ float ftanh(float x){ return 1.f - 2.f/(__expf(2.f*x)+1.f); }

// ---- transpose Wbil [1024,1024] -> WbilT (U's contraction is over Wbil's
// FIRST index; Wi/Ws need no transpose: their k-index is already contiguous)
__global__ void k_transpose_bil(const float* __restrict__ Wbil, float* __restrict__ WbilT){
  __shared__ float tile[32][33];
  int tr = blockIdx.y*32, tc = blockIdx.x*32;
  int tx = threadIdx.x, ty = threadIdx.y;
  #pragma unroll
  for (int i=0;i<32;i+=8)
    tile[ty+i][tx] = Wbil[(size_t)(tr+ty+i)*H2 + tc+tx];
  __syncthreads();
  #pragma unroll
  for (int i=0;i<32;i+=8)
    WbilT[(size_t)(tc+ty+i)*H2 + tr+tx] = tile[tx][ty+i];
}

// ---- leaves: cell (i,0): H = seq[i,:512], C = seq[i,512:], S = 0
__global__ void k_leaf(const float* __restrict__ seqt, float* __restrict__ cH,
                       float* __restrict__ cC, float* __restrict__ cS){
  int tid = blockIdx.x*256 + threadIdx.x;
  if (tid >= NB*NW*H) return;
  int b = tid/(NW*H); int r = tid%(NW*H); int i = r/H; int d = r%H;
  int cell = b*NCELL + i;                 // coff(0)==0
  cH[(size_t)cell*H + d] = seqt[(size_t)(b*NW+i)*H2 + d];
  cC[(size_t)cell*H + d] = seqt[(size_t)(b*NW+i)*H2 + H + d];
  if (d==0) cS[cell] = 0.f;
}

// ---- per-cell projections for diagonal d:
//   PI = H@Wi^T + bi + ins_bias ; PS = H@Ws^T + bs ; U = [H,C]^T Wbil
// Rounds 4-10 invariant: per-block serial time ~= per-block weight bytes /
// ~2.8 GB/s (1-2 loads in flight per wave; compiler defeats deeper register
// pipelines -- VGPR stayed 52 in r9). Levers that work: TLP and fewer bytes
// per block. So: j-group = 16 columns (384 groups) and the block's 4 waves
// split K in quarters -> 32 KB weight slice/block (4x fewer bytes) and 4x
// more blocks on tail diagonals. Deterministic 16-way LDS reduction folds
// the (wave,kk) k-slices.
// grid.x = 384 j-groups (0-159: PI, 160-319: PS, 320-383: U), grid.y = m/8.
__global__ void __launch_bounds__(256)
k_proj9(const float* __restrict__ Wi, const float* __restrict__ Ws,
        const float* __restrict__ WbilT, const float* __restrict__ bi,
        const float* __restrict__ bs,
        const float* __restrict__ cH, const float* __restrict__ cC,
        float* __restrict__ cPI, float* __restrict__ cPS, float* __restrict__ cU,
        int d, int P){
  __shared__ float As[8*512];        // [m][k], 16 KB
  __shared__ float red[16][16*8];    // [kslice][jj*8+m], 8 KB
  const int t = threadIdx.x;
  const int g = blockIdx.x;
  const int m0 = blockIdx.y*8;
  const int Mtot = NB*P;
  const int nm = min(8, Mtot-m0);

  int kind, j0;
  if (g < 160){ kind=0; j0 = g*16; }
  else if (g < 320){ kind=1; j0 = (g-160)*16; }
  else { kind=2; j0 = (g-320)*16; }

  const int wave = t>>6, lane = t&63;
  const int jj = lane & 15, kk = lane >> 4;
  const int j = j0 + jj;
  const int ksb = wave*128 + kk*32;   // this thread's 32-k segment

  int cells[8];
  #pragma unroll
  for (int m=0;m<8;m++){
    int mg = m0 + (m < nm ? m : 0);   // clamp dead rows to a valid cell
    int b = mg/P, i = mg%P;
    cells[m] = b*NCELL + coff(d) + i;
  }

  float acc[8];
  #pragma unroll
  for (int m=0;m<8;m++) acc[m] = 0.f;

  const int npass = (kind==2) ? 2 : 1;
  for (int pass=0; pass<npass; pass++){
    // stage 8 rows x 512 floats -> LDS [m][k]; 1024 float4s over 256 threads
    const float* __restrict__ srcbase = (kind==2 && pass==1) ? cC : cH;
    if (pass) __syncthreads();
    #pragma unroll
    for (int it=0; it<4; it++){
      int idx = t + it*256;
      int m = idx>>7, k4 = idx&127;
      ((float4*)As)[idx] = ((const float4*)(srcbase + (size_t)cells[m]*H))[k4];
    }
    __syncthreads();

    // thread's contiguous 128B weight run for its (j, k-segment)
    const float* __restrict__ gkt;
    if (kind==0)      gkt = Wi    + (size_t)j*H  + ksb;
    else if (kind==1) gkt = Ws    + (size_t)j*H  + ksb;
    else              gkt = WbilT + (size_t)j*H2 + (size_t)pass*H + ksb;

    float4 w[8];
    #pragma unroll
    for (int c=0;c<8;c++) w[c] = ((const float4*)gkt)[c];
    #pragma unroll
    for (int c=0;c<8;c++){
      const int kb = ksb + c*4;
      #pragma unroll
      for (int m=0;m<8;m++){
        float4 a = *(const float4*)&As[m*512 + kb];
        acc[m] = fmaf(a.x, w[c].x, acc[m]);
        acc[m] = fmaf(a.y, w[c].y, acc[m]);
        acc[m] = fmaf(a.z, w[c].z, acc[m]);
        acc[m] = fmaf(a.w, w[c].w, acc[m]);
      }
    }
  }

  // deterministic 16-way reduction over k-slices (wave*4+kk)
  #pragma unroll
  for (int m=0;m<8;m++) red[wave*4+kk][jj*8+m] = acc[m];
  __syncthreads();
  if (t < 128){
    const int rj = t>>3, m = t&7;
    float s = 0.f;
    #pragma unroll
    for (int q=0;q<16;q++) s += red[q][rj*8+m];
    const int jo = j0 + rj;
    float bias = 0.f;
    if (kind==0) bias = bi[jo] + ((jo>=H && jo<3*H)?1.f:0.f);   // ins_bias on [H,3H)
    else if (kind==1) bias = bs[jo];
    if (m < nm){
      int cell = cells[m];
      if (kind==0)      cPI[(size_t)cell*H5 + jo] = s+bias;
      else if (kind==1) cPS[(size_t)cell*H5 + jo] = s+bias;
      else              cU [(size_t)cell*H2 + jo] = s;
    }
  }
}

// ---- combine diagonal L: one block per (b,left) span of length L+1
__global__ void k_combine(const float* __restrict__ cPI, const float* __restrict__ cPS,
                          const float* __restrict__ cU,
                          float* __restrict__ cH, float* __restrict__ cC, float* __restrict__ cS,
                          int L, int P){
  const int t = threadIdx.x;
  const int b = blockIdx.x / P;
  const int left = blockIdx.x % P;
  __shared__ float compat_s[32];
  __shared__ float wts_s[32];
  __shared__ float S_s;
  const int lane = t & 63;
  const int wv = t >> 6;
  // phase 1: compat_k = U[lcell] . [H;C][rcell] + lS + rS, waves parallel over k
  for (int k=wv; k<L; k+=4){
    int lc = b*NCELL + coff(k) + left;
    int rc = b*NCELL + coff(L-1-k) + left+k+1;
    const float* U  = cU + (size_t)lc*H2;
    const float* Hr = cH + (size_t)rc*H;
    const float* Cr = cC + (size_t)rc*H;
    float p = 0.f;
    for (int i=lane; i<H; i+=64)
      p += U[i]*Hr[i] + U[H+i]*Cr[i];
    #pragma unroll
    for (int off=32; off>0; off>>=1) p += __shfl_down(p, off);
    if (lane==0) compat_s[k] = p + cS[lc] + cS[rc];
  }
  __syncthreads();
  // phase 2: softmax over k (L<=23, serial on thread 0)
  if (t==0){
    float mx = -1e30f;
    for (int k=0;k<L;k++) mx = fmaxf(mx, compat_s[k]);
    float den = 0.f;
    for (int k=0;k<L;k++){ float e = __expf(compat_s[k]-mx); wts_s[k]=e; den+=e; }
    float inv = 1.f/den, S = 0.f;
    for (int k=0;k<L;k++){ wts_s[k]*=inv; S += wts_s[k]*compat_s[k]; }
    S_s = S;
  }
  __syncthreads();
  // phase 3: gates + weighted accumulate; thread t handles dims t and t+256
  float aH0=0.f, aH1=0.f, aC0=0.f, aC1=0.f;
  const int d0 = t, d1 = t+256;
  for (int k=0;k<L;k++){
    float wk = wts_s[k];
    int lc = b*NCELL + coff(k) + left;
    int rc = b*NCELL + coff(L-1-k) + left+k+1;
    const float* PI  = cPI + (size_t)lc*H5;
    const float* PS  = cPS + (size_t)rc*H5;
    const float* lCp = cC + (size_t)lc*H;
    const float* rCp = cC + (size_t)rc*H;
    {
      float p0 = PI[d0]     + PS[d0];
      float p1 = PI[H+d0]   + PS[H+d0];
      float p2 = PI[2*H+d0] + PS[2*H+d0];
      float p3 = PI[3*H+d0] + PS[3*H+d0];
      float p4 = PI[4*H+d0] + PS[4*H+d0];
      float mem = sigm(p1)*lCp[d0] + sigm(p2)*rCp[d0] + sigm(p0)*ftanh(p3);
      float h = sigm(p4)*ftanh(mem);
      aH0 += wk*h; aC0 += wk*mem;
    }
    {
      float p0 = PI[d1]     + PS[d1];
      float p1 = PI[H+d1]   + PS[H+d1];
      float p2 = PI[2*H+d1] + PS[2*H+d1];
      float p3 = PI[3*H+d1] + PS[3*H+d1];
      float p4 = PI[4*H+d1] + PS[4*H+d1];
      float mem = sigm(p1)*lCp[d1] + sigm(p2)*rCp[d1] + sigm(p0)*ftanh(p3);
      float h = sigm(p4)*ftanh(mem);
      aH1 += wk*h; aC1 += wk*mem;
    }
  }
  int nc = b*NCELL + coff(L) + left;
  cH[(size_t)nc*H + d0] = aH0; cH[(size_t)nc*H + d1] = aH1;
  cC[(size_t)nc*H + d0] = aC0; cC[(size_t)nc*H + d1] = aC1;
  if (t==0) cS[nc] = S_s;
}

// ---- root output: concat(H, C) of cell (0, n-1)
__global__ void k_out(const float* __restrict__ cH, const float* __restrict__ cC,
                      float* __restrict__ out){
  int tid = blockIdx.x*256+threadIdx.x;
  if (tid >= NB*H2) return;
  int b = tid>>10, d = tid&1023;
  int cell = b*NCELL + 299;   // coff(23)+0
  out[tid] = (d<H) ? cH[(size_t)cell*H + d] : cC[(size_t)cell*H + (d-H)];
}

extern "C" void kernel_launch(void* const* d_in, const int* in_sizes, int n_in,
                              void* d_out, int out_size, void* d_ws, size_t ws_size,
                              hipStream_t stream){
  const float* seqt = (const float*)d_in[0];
  const float* Wi   = (const float*)d_in[1];
  const float* bi   = (const float*)d_in[2];
  const float* Ws   = (const float*)d_in[3];
  const float* bs   = (const float*)d_in[4];
  const float* Wbil = (const float*)d_in[5];
  float* out = (float*)d_out;

  float* p = (ws_size >= NEED_BYTES && g_buf == nullptr) ? (float*)d_ws : g_buf;
  float* WbilT = p; p += (size_t)H2*H2;
  float* cH  = p; p += (size_t)NB*NCELL*H;
  float* cC  = p; p += (size_t)NB*NCELL*H;
  float* cS  = p; p += (size_t)NB*NCELL;
  float* cPI = p; p += (size_t)NB*NCELL*H5;
  float* cPS = p; p += (size_t)NB*NCELL*H5;
  float* cU  = p; p += (size_t)NB*NCELL*H2;

  k_transpose_bil<<<dim3(32,32), dim3(32,8), 0, stream>>>(Wbil, WbilT);
  k_leaf<<<(NB*NW*H+255)/256, 256, 0, stream>>>(seqt, cH, cC, cS);
  k_proj9<<<dim3(384, (NB*NW+7)/8), 256, 0, stream>>>(
      Wi, Ws, WbilT, bi, bs, cH, cC, cPI, cPS, cU, 0, NW);
  for (int L=1; L<NW; L++){
    int P = NW - L;
    k_combine<<<NB*P, 256, 0, stream>>>(cPI, cPS, cU, cH, cC, cS, L, P);
    if (L < NW-1)
      k_proj9<<<dim3(384, (NB*P+7)/8), 256, 0, stream>>>(
          Wi, Ws, WbilT, bi, bs, cH, cC, cPI, cPS, cU, L, P);
  }
  k_out<<<16, 256, 0, stream>>>(cH, cC, out);
}

// Round 12
// 1031.049 us; speedup vs baseline: 3.5680x; 1.2653x over previous
//
#include <hip/hip_runtime.h>
#include <math.h>

#define NB 4
#define NW 24
#define H 512
#define H2 1024
#define H5 2560
#define NCELL 300   // n*(n+1)/2 valid cells per batch
#define NEED_BYTES ((size_t)72<<20)

// Private fallback workspace: allocated ONCE at library load (outside
// kernel_launch, so graph capture never sees the hipMalloc). d_ws proved too
// small in round 1 (44.9MB layout corrupted adjacent harness allocations).
static float* g_buf = nullptr;
__attribute__((constructor)) static void dio_alloc_ws(){
  (void)hipMalloc((void**)&g_buf, NEED_BYTES);
}

typedef __attribute__((ext_vector_type(8))) short bf16x8;   // 8 bf16 (4 VGPRs)
typedef __attribute__((ext_vector_type(4))) float f32x4;

__device__ __forceinline__ int coff(int l){ return l*NW - (l*(l-1))/2; }
__device__ __forceinline__ float sigm(float x){ return 1.f/(1.f+__expf(-x)); }
__device__ __forceinline__ float ftanh(float x){ return 1.f - 2.f/(__expf(2.f*x)+1.f); }

__device__ __forceinline__ unsigned short f2b(float x){  // fp32 -> bf16 RNE
  unsigned int u = __float_as_uint(x);
  u += 0x7FFF + ((u>>16)&1);
  return (unsigned short)(u>>16);
}
__device__ __forceinline__ float b2f(unsigned short h){
  return __uint_as_float(((unsigned int)h)<<16);
}
// split-bf16: x ~= hi + lo with effective 2^-17 relative error
__device__ __forceinline__ void split_store(unsigned short* __restrict__ ph,
                                            unsigned short* __restrict__ pl,
                                            size_t idx, float x){
  unsigned short h = f2b(x);
  ph[idx] = h;
  pl[idx] = f2b(x - b2f(h));
}

// ---- split-convert Wi and Ws (k-contiguous rows already)
__global__ void k_prep_w(const float* __restrict__ Wi, const float* __restrict__ Ws,
                         unsigned short* __restrict__ WiBh, unsigned short* __restrict__ WiBl,
                         unsigned short* __restrict__ WsBh, unsigned short* __restrict__ WsBl){
  int i = blockIdx.x*256 + threadIdx.x;
  const int n = H5*H;
  if (i < n)            split_store(WiBh, WiBl, i, Wi[i]);
  else if (i < 2*n)     split_store(WsBh, WsBl, i-n, Ws[i-n]);
}

// ---- transpose+split Wbil [k][j] -> WbilT{h,l} [j][k]
__global__ void k_prep_bil(const float* __restrict__ Wbil,
                           unsigned short* __restrict__ WbilTh,
                           unsigned short* __restrict__ WbilTl){
  __shared__ float tile[32][33];
  int tr = blockIdx.y*32, tc = blockIdx.x*32;
  int tx = threadIdx.x, ty = threadIdx.y;
  #pragma unroll
  for (int i=0;i<32;i+=8)
    tile[ty+i][tx] = Wbil[(size_t)(tr+ty+i)*H2 + tc+tx];
  __syncthreads();
  #pragma unroll
  for (int i=0;i<32;i+=8)
    split_store(WbilTh, WbilTl, (size_t)(tc+ty+i)*H2 + tr+tx, tile[tx][ty+i]);
}

// ---- leaves: fp32 chart + split-bf16 chart
__global__ void k_leaf(const float* __restrict__ seqt, float* __restrict__ cH,
                       float* __restrict__ cC, float* __restrict__ cS,
                       unsigned short* __restrict__ cHbh, unsigned short* __restrict__ cHbl,
                       unsigned short* __restrict__ cCbh, unsigned short* __restrict__ cCbl){
  int tid = blockIdx.x*256 + threadIdx.x;
  if (tid >= NB*NW*H) return;
  int b = tid/(NW*H); int r = tid%(NW*H); int i = r/H; int d = r%H;
  size_t idx = (size_t)(b*NCELL + i)*H + d;     // coff(0)==0
  float hv = seqt[(size_t)(b*NW+i)*H2 + d];
  float cv = seqt[(size_t)(b*NW+i)*H2 + H + d];
  cH[idx]=hv; cC[idx]=cv;
  split_store(cHbh,cHbl,idx,hv);
  split_store(cCbh,cCbl,idx,cv);
  if (d==0) cS[b*NCELL+i] = 0.f;
}

// ---- MFMA projections for diagonal d:
//   PI = H@Wi^T+bi+ins_bias ; PS = H@Ws^T+bs ; U = [H,C]^T Wbil
// One wave per 16m x 16j tile. A = activations (m=lane&15, k=quad*8+i),
// B = weight rows j (n=lane&15, k=quad*8+i) -> 4 16B loads per K=32 step.
// Split-bf16: acc += Ah*Bh + Ah*Bl + Al*Bh + Al*Bl (fp32 acc).
// Straight-line batches of 8 steps keep 32 loads in flight (no rotating
// buffers -- rounds 4-9 showed the compiler collapses those).
// grid.x = 384 j-tiles (0-159: PI, 160-319: PS, 320-383: U), grid.y = m/16.
__global__ void __launch_bounds__(64, 2)
k_projM(const unsigned short* __restrict__ WiBh, const unsigned short* __restrict__ WiBl,
        const unsigned short* __restrict__ WsBh, const unsigned short* __restrict__ WsBl,
        const unsigned short* __restrict__ WbilTh, const unsigned short* __restrict__ WbilTl,
        const float* __restrict__ bi, const float* __restrict__ bs,
        const unsigned short* __restrict__ cHbh, const unsigned short* __restrict__ cHbl,
        const unsigned short* __restrict__ cCbh, const unsigned short* __restrict__ cCbl,
        float* __restrict__ cPI, float* __restrict__ cPS, float* __restrict__ cU,
        int d, int P)
{
  const int lane = threadIdx.x;
  const int jt = blockIdx.x;
  const int m0 = blockIdx.y*16;
  const int Mtot = NB*P;
  const int nm = min(16, Mtot-m0);

  int kind, j0;
  if (jt < 160){ kind=0; j0 = jt*16; }
  else if (jt < 320){ kind=1; j0 = (jt-160)*16; }
  else { kind=2; j0 = (jt-320)*16; }

  const int r = lane & 15;   // A row (m) / B col (j) / D col
  const int q = lane >> 4;   // quad: k = q*8 + i

  int mg = m0 + (r < nm ? r : 0);
  const size_t arow = (size_t)((mg/P)*NCELL + coff(d) + mg%P)*H + q*8;

  const unsigned short *bhp, *blp; size_t brow;
  if (kind==0){ bhp=WiBh; blp=WiBl; brow=(size_t)(j0+r)*H + q*8; }
  else if (kind==1){ bhp=WsBh; blp=WsBl; brow=(size_t)(j0+r)*H + q*8; }
  else { bhp=WbilTh; blp=WbilTl; brow=(size_t)(j0+r)*H2 + q*8; }

  f32x4 acc = {0.f,0.f,0.f,0.f};

  const int npass = (kind==2) ? 2 : 1;
  for (int pass=0; pass<npass; pass++){
    const unsigned short* ah = (pass==0) ? cHbh : cCbh;
    const unsigned short* al = (pass==0) ? cHbl : cCbl;
    const size_t boff = brow + (size_t)pass*H;   // U pass 2: k=512..1023 of WbilT rows
    #pragma unroll
    for (int batch=0; batch<2; batch++){
      bf16x8 fah[8], fal[8], fbh[8], fbl[8];
      #pragma unroll
      for (int s=0;s<8;s++){
        const int ko = (batch*8+s)*32;
        fah[s] = *(const bf16x8*)(ah + arow + ko);
        fal[s] = *(const bf16x8*)(al + arow + ko);
        fbh[s] = *(const bf16x8*)(bhp + boff + ko);
        fbl[s] = *(const bf16x8*)(blp + boff + ko);
      }
      #pragma unroll
      for (int s=0;s<8;s++){
        acc = __builtin_amdgcn_mfma_f32_16x16x32_bf16(fah[s], fbh[s], acc, 0,0,0);
        acc = __builtin_amdgcn_mfma_f32_16x16x32_bf16(fah[s], fbl[s], acc, 0,0,0);
        acc = __builtin_amdgcn_mfma_f32_16x16x32_bf16(fal[s], fbh[s], acc, 0,0,0);
        acc = __builtin_amdgcn_mfma_f32_16x16x32_bf16(fal[s], fbl[s], acc, 0,0,0);
      }
    }
  }

  // D layout (m89): col = lane&15 (j), row = quad*4 + reg (m)
  const int jo = j0 + r;
  float bias = 0.f;
  if (kind==0) bias = bi[jo] + ((jo>=H && jo<3*H)?1.f:0.f);   // ins_bias on [H,3H)
  else if (kind==1) bias = bs[jo];
  #pragma unroll
  for (int reg=0; reg<4; reg++){
    const int m = q*4 + reg;
    if (m < nm){
      const int mg2 = m0 + m;
      const size_t cell = (size_t)((mg2/P)*NCELL + coff(d) + mg2%P);
      const float v = acc[reg];
      if (kind==0)      cPI[cell*H5 + jo] = v + bias;
      else if (kind==1) cPS[cell*H5 + jo] = v + bias;
      else              cU [cell*H2 + jo] = v;
    }
  }
}

// ---- combine diagonal L: one block per (b,left) span; also refresh bf16 chart
__global__ void k_combine(const float* __restrict__ cPI, const float* __restrict__ cPS,
                          const float* __restrict__ cU,
                          float* __restrict__ cH, float* __restrict__ cC, float* __restrict__ cS,
                          unsigned short* __restrict__ cHbh, unsigned short* __restrict__ cHbl,
                          unsigned short* __restrict__ cCbh, unsigned short* __restrict__ cCbl,
                          int L, int P){
  const int t = threadIdx.x;
  const int b = blockIdx.x / P;
  const int left = blockIdx.x % P;
  __shared__ float compat_s[32];
  __shared__ float wts_s[32];
  __shared__ float S_s;
  const int lane = t & 63;
  const int wv = t >> 6;
  for (int k=wv; k<L; k+=4){
    int lc = b*NCELL + coff(k) + left;
    int rc = b*NCELL + coff(L-1-k) + left+k+1;
    const float* U  = cU + (size_t)lc*H2;
    const float* Hr = cH + (size_t)rc*H;
    const float* Cr = cC + (size_t)rc*H;
    float p = 0.f;
    for (int i=lane; i<H; i+=64)
      p += U[i]*Hr[i] + U[H+i]*Cr[i];
    #pragma unroll
    for (int off=32; off>0; off>>=1) p += __shfl_down(p, off);
    if (lane==0) compat_s[k] = p + cS[lc] + cS[rc];
  }
  __syncthreads();
  if (t==0){
    float mx = -1e30f;
    for (int k=0;k<L;k++) mx = fmaxf(mx, compat_s[k]);
    float den = 0.f;
    for (int k=0;k<L;k++){ float e = __expf(compat_s[k]-mx); wts_s[k]=e; den+=e; }
    float inv = 1.f/den, S = 0.f;
    for (int k=0;k<L;k++){ wts_s[k]*=inv; S += wts_s[k]*compat_s[k]; }
    S_s = S;
  }
  __syncthreads();
  float aH0=0.f, aH1=0.f, aC0=0.f, aC1=0.f;
  const int d0 = t, d1 = t+256;
  for (int k=0;k<L;k++){
    float wk = wts_s[k];
    int lc = b*NCELL + coff(k) + left;
    int rc = b*NCELL + coff(L-1-k) + left+k+1;
    const float* PI  = cPI + (size_t)lc*H5;
    const float* PS  = cPS + (size_t)rc*H5;
    const float* lCp = cC + (size_t)lc*H;
    const float* rCp = cC + (size_t)rc*H;
    {
      float p0 = PI[d0]     + PS[d0];
      float p1 = PI[H+d0]   + PS[H+d0];
      float p2 = PI[2*H+d0] + PS[2*H+d0];
      float p3 = PI[3*H+d0] + PS[3*H+d0];
      float p4 = PI[4*H+d0] + PS[4*H+d0];
      float mem = sigm(p1)*lCp[d0] + sigm(p2)*rCp[d0] + sigm(p0)*ftanh(p3);
      float h = sigm(p4)*ftanh(mem);
      aH0 += wk*h; aC0 += wk*mem;
    }
    {
      float p0 = PI[d1]     + PS[d1];
      float p1 = PI[H+d1]   + PS[H+d1];
      float p2 = PI[2*H+d1] + PS[2*H+d1];
      float p3 = PI[3*H+d1] + PS[3*H+d1];
      float p4 = PI[4*H+d1] + PS[4*H+d1];
      float mem = sigm(p1)*lCp[d1] + sigm(p2)*rCp[d1] + sigm(p0)*ftanh(p3);
      float h = sigm(p4)*ftanh(mem);
      aH1 += wk*h; aC1 += wk*mem;
    }
  }
  size_t nc = (size_t)(b*NCELL + coff(L) + left);
  cH[nc*H + d0] = aH0; cH[nc*H + d1] = aH1;
  cC[nc*H + d0] = aC0; cC[nc*H + d1] = aC1;
  split_store(cHbh,cHbl, nc*H + d0, aH0);
  split_store(cHbh,cHbl, nc*H + d1, aH1);
  split_store(cCbh,cCbl, nc*H + d0, aC0);
  split_store(cCbh,cCbl, nc*H + d1, aC1);
  if (t==0) cS[nc] = S_s;
}

// ---- root output: concat(H, C) of cell (0, n-1)
__global__ void k_out(const float* __restrict__ cH, const float* __restrict__ cC,
                      float* __restrict__ out){
  int tid = blockIdx.x*256+threadIdx.x;
  if (tid >= NB*H2) return;
  int b = tid>>10, d = tid&1023;
  int cell = b*NCELL + 299;   // coff(23)+0
  out[tid] = (d<H) ? cH[(size_t)cell*H + d] : cC[(size_t)cell*H + (d-H)];
}

extern "C" void kernel_launch(void* const* d_in, const int* in_sizes, int n_in,
                              void* d_out, int out_size, void* d_ws, size_t ws_size,
                              hipStream_t stream){
  const float* seqt = (const float*)d_in[0];
  const float* Wi   = (const float*)d_in[1];
  const float* bi   = (const float*)d_in[2];
  const float* Ws   = (const float*)d_in[3];
  const float* bs   = (const float*)d_in[4];
  const float* Wbil = (const float*)d_in[5];
  float* out = (float*)d_out;

  float* p = (ws_size >= NEED_BYTES && g_buf == nullptr) ? (float*)d_ws : g_buf;
  float* cH  = p; p += (size_t)NB*NCELL*H;
  float* cC  = p; p += (size_t)NB*NCELL*H;
  float* cS  = p; p += (size_t)NB*NCELL;
  float* cPI = p; p += (size_t)NB*NCELL*H5;
  float* cPS = p; p += (size_t)NB*NCELL*H5;
  float* cU  = p; p += (size_t)NB*NCELL*H2;
  unsigned short* u = (unsigned short*)p;
  unsigned short* WiBh   = u; u += (size_t)H5*H;
  unsigned short* WiBl   = u; u += (size_t)H5*H;
  unsigned short* WsBh   = u; u += (size_t)H5*H;
  unsigned short* WsBl   = u; u += (size_t)H5*H;
  unsigned short* WbilTh = u; u += (size_t)H2*H2;
  unsigned short* WbilTl = u; u += (size_t)H2*H2;
  unsigned short* cHbh   = u; u += (size_t)NB*NCELL*H;
  unsigned short* cHbl   = u; u += (size_t)NB*NCELL*H;
  unsigned short* cCbh   = u; u += (size_t)NB*NCELL*H;
  unsigned short* cCbl   = u; u += (size_t)NB*NCELL*H;

  k_prep_w<<<(2*H5*H+255)/256, 256, 0, stream>>>(Wi, Ws, WiBh, WiBl, WsBh, WsBl);
  k_prep_bil<<<dim3(32,32), dim3(32,8), 0, stream>>>(Wbil, WbilTh, WbilTl);
  k_leaf<<<(NB*NW*H+255)/256, 256, 0, stream>>>(seqt, cH, cC, cS, cHbh, cHbl, cCbh, cCbl);

  k_projM<<<dim3(384, (NB*NW+15)/16), 64, 0, stream>>>(
      WiBh, WiBl, WsBh, WsBl, WbilTh, WbilTl, bi, bs,
      cHbh, cHbl, cCbh, cCbl, cPI, cPS, cU, 0, NW);
  for (int L=1; L<NW; L++){
    int P = NW - L;
    k_combine<<<NB*P, 256, 0, stream>>>(cPI, cPS, cU, cH, cC, cS,
                                        cHbh, cHbl, cCbh, cCbl, L, P);
    if (L < NW-1)
      k_projM<<<dim3(384, (NB*P+15)/16), 64, 0, stream>>>(
          WiBh, WiBl, WsBh, WsBl, WbilTh, WbilTl, bi, bs,
          cHbh, cHbl, cCbh, cCbl, cPI, cPS, cU, L, P);
  }
  k_out<<<16, 256, 0, stream>>>(cH, cC, out);
}

// Round 13
// 846.223 us; speedup vs baseline: 4.3473x; 1.2184x over previous
//
#include <hip/hip_runtime.h>
#include <math.h>

#define NB 4
#define NW 24
#define H 512
#define H2 1024
#define H5 2560
#define NCELL 300   // n*(n+1)/2 valid cells per batch
#define NEED_BYTES ((size_t)72<<20)

// Private fallback workspace: allocated ONCE at library load (outside
// kernel_launch, so graph capture never sees the hipMalloc). d_ws proved too
// small in round 1 (44.9MB layout corrupted adjacent harness allocations).
static float* g_buf = nullptr;
__attribute__((constructor)) static void dio_alloc_ws(){
  (void)hipMalloc((void**)&g_buf, NEED_BYTES);
}

typedef __attribute__((ext_vector_type(8))) short bf16x8;   // 8 bf16 (4 VGPRs)
typedef __attribute__((ext_vector_type(4))) float f32x4;
typedef unsigned short ushort_t;

__device__ __forceinline__ int coff(int l){ return l*NW - (l*(l-1))/2; }
__device__ __forceinline__ float sigm(float x){ return 1.f/(1.f+__expf(-x)); }
__device__ __forceinline__ float ftanh(float x){ return 1.f - 2.f/(__expf(2.f*x)+1.f); }

__device__ __forceinline__ ushort_t f2b(float x){  // fp32 -> bf16 RNE
  unsigned int u = __float_as_uint(x);
  u += 0x7FFF + ((u>>16)&1);
  return (ushort_t)(u>>16);
}
__device__ __forceinline__ float b2f(ushort_t h){
  return __uint_as_float(((unsigned int)h)<<16);
}
// split-bf16: x ~= hi + lo with effective ~2^-17 relative error
__device__ __forceinline__ void split_store(ushort_t* __restrict__ ph,
                                            ushort_t* __restrict__ pl,
                                            size_t idx, float x){
  ushort_t h = f2b(x);
  ph[idx] = h;
  pl[idx] = f2b(x - b2f(h));
}

// ---- merged init: split Wi/Ws, transpose+split Wbil, leaves
__global__ void k_init(const float* __restrict__ seqt,
                       const float* __restrict__ Wi, const float* __restrict__ Ws,
                       const float* __restrict__ Wbil,
                       ushort_t* __restrict__ WiBh, ushort_t* __restrict__ WiBl,
                       ushort_t* __restrict__ WsBh, ushort_t* __restrict__ WsBl,
                       ushort_t* __restrict__ WbilTh, ushort_t* __restrict__ WbilTl,
                       float* __restrict__ cH, float* __restrict__ cC, float* __restrict__ cS,
                       ushort_t* __restrict__ cHbh, ushort_t* __restrict__ cHbl,
                       ushort_t* __restrict__ cCbh, ushort_t* __restrict__ cCbl){
  const int blk = blockIdx.x, t = threadIdx.x;
  if (blk < 10240){                       // Wi/Ws split (2*H5*H elems exactly)
    int i = blk*256 + t;
    const int n = H5*H;
    if (i < n) split_store(WiBh, WiBl, i, Wi[i]);
    else       split_store(WsBh, WsBl, i-n, Ws[i-n]);
  } else if (blk < 11264){                // Wbil transpose+split (1024 tiles)
    __shared__ float tile[32][33];
    int tb = blk - 10240;
    int tr = (tb>>5)*32, tc = (tb&31)*32;
    int tx = t & 31, ty = t >> 5;         // 32 x 8
    #pragma unroll
    for (int i=0;i<32;i+=8)
      tile[ty+i][tx] = Wbil[(size_t)(tr+ty+i)*H2 + tc+tx];
    __syncthreads();
    #pragma unroll
    for (int i=0;i<32;i+=8)
      split_store(WbilTh, WbilTl, (size_t)(tc+ty+i)*H2 + tr+tx, tile[tx][ty+i]);
  } else {                                // leaves (192 blocks)
    int tid = (blk-11264)*256 + t;
    if (tid < NB*NW*H){
      int b = tid/(NW*H); int r = tid%(NW*H); int i = r/H; int d = r%H;
      size_t idx = (size_t)(b*NCELL + i)*H + d;     // coff(0)==0
      float hv = seqt[(size_t)(b*NW+i)*H2 + d];
      float cv = seqt[(size_t)(b*NW+i)*H2 + H + d];
      cH[idx]=hv; cC[idx]=cv;
      split_store(cHbh,cHbl,idx,hv);
      split_store(cCbh,cCbl,idx,cv);
      if (d==0) cS[b*NCELL+i] = 0.f;
    }
  }
}

__device__ __forceinline__ void mfma3(f32x4& acc, bf16x8 ah, bf16x8 al,
                                      bf16x8 bh, bf16x8 bl){
  // split product; lo*lo (~2^-34 rel) dropped
  acc = __builtin_amdgcn_mfma_f32_16x16x32_bf16(ah, bh, acc, 0,0,0);
  acc = __builtin_amdgcn_mfma_f32_16x16x32_bf16(ah, bl, acc, 0,0,0);
  acc = __builtin_amdgcn_mfma_f32_16x16x32_bf16(al, bh, acc, 0,0,0);
}

// ---- MFMA projections, K-split across the block's 4 waves.
// Rounds 4-12 invariant: per-wave global loads serialize at ~450cy each, so
// dispatch time ~ per-wave load count. r12: U-wave = 128 loads = ~26us. Here
// each wave owns a K-quarter -> 16 loads (PI/PS) / 32 (U); partial f32x4
// accs reduced deterministically via LDS. Fragment mappings (A: m=lane&15,
// k=quad*8+i; D: col=lane&15, row=quad*4+reg) verified correct by r12 pass.
// grid.x = 384 j-tiles (0-159: PI, 160-319: PS, 320-383: U), grid.y = m/16.
__global__ void __launch_bounds__(256)
k_projN(const ushort_t* __restrict__ WiBh, const ushort_t* __restrict__ WiBl,
        const ushort_t* __restrict__ WsBh, const ushort_t* __restrict__ WsBl,
        const ushort_t* __restrict__ WbilTh, const ushort_t* __restrict__ WbilTl,
        const float* __restrict__ bi, const float* __restrict__ bs,
        const ushort_t* __restrict__ cHbh, const ushort_t* __restrict__ cHbl,
        const ushort_t* __restrict__ cCbh, const ushort_t* __restrict__ cCbl,
        float* __restrict__ cPI, float* __restrict__ cPS, float* __restrict__ cU,
        int d, int P)
{
  __shared__ f32x4 red[4][64];
  const int t = threadIdx.x, wave = t>>6, lane = t&63;
  const int jt = blockIdx.x;
  const int m0 = blockIdx.y*16;
  const int Mtot = NB*P;
  const int nm = min(16, Mtot-m0);

  int kind, j0;
  if (jt < 160){ kind=0; j0 = jt*16; }
  else if (jt < 320){ kind=1; j0 = (jt-160)*16; }
  else { kind=2; j0 = (jt-320)*16; }

  const int r = lane & 15;   // A row (m) / B row (j) / D col
  const int q = lane >> 4;   // quad: k = q*8 + i

  int mg = m0 + (r < nm ? r : 0);
  const size_t arow = (size_t)((mg/P)*NCELL + coff(d) + mg%P)*H;

  f32x4 acc = {0.f,0.f,0.f,0.f};

  if (kind < 2){
    const ushort_t* bh_ = (kind==0 ? WiBh : WsBh) + (size_t)(j0+r)*H;
    const ushort_t* bl_ = (kind==0 ? WiBl : WsBl) + (size_t)(j0+r)*H;
    const int ks = wave*128 + q*8;          // this wave's K-quarter
    bf16x8 fah[4], fal[4], fbh[4], fbl[4];
    #pragma unroll
    for (int s=0;s<4;s++){
      const int ko = ks + s*32;
      fah[s] = *(const bf16x8*)(cHbh + arow + ko);
      fal[s] = *(const bf16x8*)(cHbl + arow + ko);
      fbh[s] = *(const bf16x8*)(bh_ + ko);
      fbl[s] = *(const bf16x8*)(bl_ + ko);
    }
    #pragma unroll
    for (int s=0;s<4;s++) mfma3(acc, fah[s], fal[s], fbh[s], fbl[s]);
  } else {
    // U: global k in [0,1024); waves 0,1 -> H chart, 2,3 -> C chart
    const ushort_t* bh_ = WbilTh + (size_t)(j0+r)*H2;
    const ushort_t* bl_ = WbilTl + (size_t)(j0+r)*H2;
    const ushort_t* ah_ = (wave<2 ? cHbh : cCbh) + arow;
    const ushort_t* al_ = (wave<2 ? cHbl : cCbl) + arow;
    const int kg0 = wave*256;               // global k base
    const int ka0 = kg0 & 511;              // chart k base
    #pragma unroll
    for (int gz=0; gz<2; gz++){             // 2 groups of 4 steps
      bf16x8 fah[4], fal[4], fbh[4], fbl[4];
      #pragma unroll
      for (int s=0;s<4;s++){
        const int so = (gz*4+s)*32 + q*8;
        fah[s] = *(const bf16x8*)(ah_ + ka0 + so);
        fal[s] = *(const bf16x8*)(al_ + ka0 + so);
        fbh[s] = *(const bf16x8*)(bh_ + kg0 + so);
        fbl[s] = *(const bf16x8*)(bl_ + kg0 + so);
      }
      #pragma unroll
      for (int s=0;s<4;s++) mfma3(acc, fah[s], fal[s], fbh[s], fbl[s]);
    }
  }

  red[wave][lane] = acc;
  __syncthreads();
  if (wave == 0){
    f32x4 s0 = red[0][lane], s1 = red[1][lane], s2 = red[2][lane], s3 = red[3][lane];
    f32x4 tot = (s0+s1) + (s2+s3);          // fixed order -> deterministic
    const int jo = j0 + r;
    float bias = 0.f;
    if (kind==0) bias = bi[jo] + ((jo>=H && jo<3*H)?1.f:0.f);   // ins_bias on [H,3H)
    else if (kind==1) bias = bs[jo];
    #pragma unroll
    for (int reg=0; reg<4; reg++){
      const int m = q*4 + reg;
      if (m < nm){
        const int mg2 = m0 + m;
        const size_t cell = (size_t)((mg2/P)*NCELL + coff(d) + mg2%P);
        const float v = tot[reg];
        if (kind==0)      cPI[cell*H5 + jo] = v + bias;
        else if (kind==1) cPS[cell*H5 + jo] = v + bias;
        else              cU [cell*H2 + jo] = v;
      }
    }
  }
}

// ---- combine diagonal L: one block per (b,left) span; float2-vectorized
// (thread owns dims 2t, 2t+1 -> half the load-instruction chain of r12).
__global__ void k_combine(const float* __restrict__ cPI, const float* __restrict__ cPS,
                          const float* __restrict__ cU,
                          float* __restrict__ cH, float* __restrict__ cC, float* __restrict__ cS,
                          ushort_t* __restrict__ cHbh, ushort_t* __restrict__ cHbl,
                          ushort_t* __restrict__ cCbh, ushort_t* __restrict__ cCbl,
                          int L, int P){
  const int t = threadIdx.x;
  const int b = blockIdx.x / P;
  const int left = blockIdx.x % P;
  __shared__ float compat_s[32];
  __shared__ float wts_s[32];
  __shared__ float S_s;
  const int lane = t & 63;
  const int wv = t >> 6;
  // phase 1: compat_k = U[lcell].[H;C][rcell] + lS + rS (float2 strided)
  for (int k=wv; k<L; k+=4){
    int lc = b*NCELL + coff(k) + left;
    int rc = b*NCELL + coff(L-1-k) + left+k+1;
    const float2* U2l = (const float2*)(cU + (size_t)lc*H2);
    const float2* U2h = (const float2*)(cU + (size_t)lc*H2 + H);
    const float2* Hr2 = (const float2*)(cH + (size_t)rc*H);
    const float2* Cr2 = (const float2*)(cC + (size_t)rc*H);
    float p = 0.f;
    #pragma unroll
    for (int it=0; it<4; it++){
      int i = lane + it*64;                 // float2 index 0..255
      float2 u0 = U2l[i], u1 = U2h[i], hh = Hr2[i], cc = Cr2[i];
      p += u0.x*hh.x + u0.y*hh.y + u1.x*cc.x + u1.y*cc.y;
    }
    #pragma unroll
    for (int off=32; off>0; off>>=1) p += __shfl_down(p, off);
    if (lane==0) compat_s[k] = p + cS[lc] + cS[rc];
  }
  __syncthreads();
  // phase 2: softmax over k (L<=23, serial on thread 0)
  if (t==0){
    float mx = -1e30f;
    for (int k=0;k<L;k++) mx = fmaxf(mx, compat_s[k]);
    float den = 0.f;
    for (int k=0;k<L;k++){ float e = __expf(compat_s[k]-mx); wts_s[k]=e; den+=e; }
    float inv = 1.f/den, S = 0.f;
    for (int k=0;k<L;k++){ wts_s[k]*=inv; S += wts_s[k]*compat_s[k]; }
    S_s = S;
  }
  __syncthreads();
  // phase 3: gates + weighted accumulate; thread t owns dims 2t, 2t+1
  float2 aH = {0.f,0.f}, aC = {0.f,0.f};
  for (int k=0;k<L;k++){
    float wk = wts_s[k];
    int lc = b*NCELL + coff(k) + left;
    int rc = b*NCELL + coff(L-1-k) + left+k+1;
    const float2* PI2 = (const float2*)(cPI + (size_t)lc*H5);
    const float2* PS2 = (const float2*)(cPS + (size_t)rc*H5);
    float2 x0=PI2[t],        y0=PS2[t];
    float2 x1=PI2[256+t],    y1=PS2[256+t];
    float2 x2=PI2[512+t],    y2=PS2[512+t];
    float2 x3=PI2[768+t],    y3=PS2[768+t];
    float2 x4=PI2[1024+t],   y4=PS2[1024+t];
    float2 lc2 = ((const float2*)(cC + (size_t)lc*H))[t];
    float2 rc2 = ((const float2*)(cC + (size_t)rc*H))[t];
    {
      float p0=x0.x+y0.x, p1=x1.x+y1.x, p2=x2.x+y2.x, p3=x3.x+y3.x, p4=x4.x+y4.x;
      float mem = sigm(p1)*lc2.x + sigm(p2)*rc2.x + sigm(p0)*ftanh(p3);
      float h = sigm(p4)*ftanh(mem);
      aH.x += wk*h; aC.x += wk*mem;
    }
    {
      float p0=x0.y+y0.y, p1=x1.y+y1.y, p2=x2.y+y2.y, p3=x3.y+y3.y, p4=x4.y+y4.y;
      float mem = sigm(p1)*lc2.y + sigm(p2)*rc2.y + sigm(p0)*ftanh(p3);
      float h = sigm(p4)*ftanh(mem);
      aH.y += wk*h; aC.y += wk*mem;
    }
  }
  size_t nc = (size_t)(b*NCELL + coff(L) + left);
  ((float2*)(cH + nc*H))[t] = aH;
  ((float2*)(cC + nc*H))[t] = aC;
  split_store(cHbh,cHbl, nc*H + 2*t,   aH.x);
  split_store(cHbh,cHbl, nc*H + 2*t+1, aH.y);
  split_store(cCbh,cCbl, nc*H + 2*t,   aC.x);
  split_store(cCbh,cCbl, nc*H + 2*t+1, aC.y);
  if (t==0) cS[nc] = S_s;
}

// ---- root output: concat(H, C) of cell (0, n-1)
__global__ void k_out(const float* __restrict__ cH, const float* __restrict__ cC,
                      float* __restrict__ out){
  int tid = blockIdx.x*256+threadIdx.x;
  if (tid >= NB*H2) return;
  int b = tid>>10, d = tid&1023;
  int cell = b*NCELL + 299;   // coff(23)+0
  out[tid] = (d<H) ? cH[(size_t)cell*H + d] : cC[(size_t)cell*H + (d-H)];
}

extern "C" void kernel_launch(void* const* d_in, const int* in_sizes, int n_in,
                              void* d_out, int out_size, void* d_ws, size_t ws_size,
                              hipStream_t stream){
  const float* seqt = (const float*)d_in[0];
  const float* Wi   = (const float*)d_in[1];
  const float* bi   = (const float*)d_in[2];
  const float* Ws   = (const float*)d_in[3];
  const float* bs   = (const float*)d_in[4];
  const float* Wbil = (const float*)d_in[5];
  float* out = (float*)d_out;

  float* p = (ws_size >= NEED_BYTES && g_buf == nullptr) ? (float*)d_ws : g_buf;
  float* cH  = p; p += (size_t)NB*NCELL*H;
  float* cC  = p; p += (size_t)NB*NCELL*H;
  float* cS  = p; p += (size_t)NB*NCELL;
  float* cPI = p; p += (size_t)NB*NCELL*H5;
  float* cPS = p; p += (size_t)NB*NCELL*H5;
  float* cU  = p; p += (size_t)NB*NCELL*H2;
  ushort_t* u = (ushort_t*)p;
  ushort_t* WiBh   = u; u += (size_t)H5*H;
  ushort_t* WiBl   = u; u += (size_t)H5*H;
  ushort_t* WsBh   = u; u += (size_t)H5*H;
  ushort_t* WsBl   = u; u += (size_t)H5*H;
  ushort_t* WbilTh = u; u += (size_t)H2*H2;
  ushort_t* WbilTl = u; u += (size_t)H2*H2;
  ushort_t* cHbh   = u; u += (size_t)NB*NCELL*H;
  ushort_t* cHbl   = u; u += (size_t)NB*NCELL*H;
  ushort_t* cCbh   = u; u += (size_t)NB*NCELL*H;
  ushort_t* cCbl   = u; u += (size_t)NB*NCELL*H;

  k_init<<<11456, 256, 0, stream>>>(seqt, Wi, Ws, Wbil,
      WiBh, WiBl, WsBh, WsBl, WbilTh, WbilTl,
      cH, cC, cS, cHbh, cHbl, cCbh, cCbl);

  k_projN<<<dim3(384, (NB*NW+15)/16), 256, 0, stream>>>(
      WiBh, WiBl, WsBh, WsBl, WbilTh, WbilTl, bi, bs,
      cHbh, cHbl, cCbh, cCbl, cPI, cPS, cU, 0, NW);
  for (int L=1; L<NW; L++){
    int P = NW - L;
    k_combine<<<NB*P, 256, 0, stream>>>(cPI, cPS, cU, cH, cC, cS,
                                        cHbh, cHbl, cCbh, cCbl, L, P);
    if (L < NW-1)
      k_projN<<<dim3(384, (NB*P+15)/16), 256, 0, stream>>>(
          WiBh, WiBl, WsBh, WsBl, WbilTh, WbilTl, bi, bs,
          cHbh, cHbl, cCbh, cCbl, cPI, cPS, cU, L, P);
  }
  k_out<<<16, 256, 0, stream>>>(cH, cC, out);
}

// Round 14
// 690.764 us; speedup vs baseline: 5.3256x; 1.2251x over previous
//
#include <hip/hip_runtime.h>
#include <math.h>

#define NB 4
#define NW 24
#define H 512
#define H2 1024
#define H5 2560
#define NCELL 300   // n*(n+1)/2 valid cells per batch
#define NEED_BYTES ((size_t)72<<20)

// Private fallback workspace: allocated ONCE at library load (outside
// kernel_launch, so graph capture never sees the hipMalloc). d_ws proved too
// small in round 1 (44.9MB layout corrupted adjacent harness allocations).
static float* g_buf = nullptr;
__attribute__((constructor)) static void dio_alloc_ws(){
  (void)hipMalloc((void**)&g_buf, NEED_BYTES);
}

typedef __attribute__((ext_vector_type(8))) short bf16x8;   // 8 bf16 (4 VGPRs)
typedef __attribute__((ext_vector_type(4))) float f32x4;
typedef unsigned short ushort_t;

__device__ __forceinline__ int coff(int l){ return l*NW - (l*(l-1))/2; }
__device__ __forceinline__ float sigm(float x){ return 1.f/(1.f+__expf(-x)); }
__device__ __forceinline__ float ftanh(float x){ return 1.f - 2.f/(__expf(2.f*x)+1.f); }

__device__ __forceinline__ ushort_t f2b(float x){  // fp32 -> bf16 RNE
  unsigned int u = __float_as_uint(x);
  u += 0x7FFF + ((u>>16)&1);
  return (ushort_t)(u>>16);
}
__device__ __forceinline__ float b2f(ushort_t h){
  return __uint_as_float(((unsigned int)h)<<16);
}
// split-bf16: x ~= hi + lo with effective ~2^-17 relative error
__device__ __forceinline__ void split_store(ushort_t* __restrict__ ph,
                                            ushort_t* __restrict__ pl,
                                            size_t idx, float x){
  ushort_t h = f2b(x);
  ph[idx] = h;
  pl[idx] = f2b(x - b2f(h));
}

// ---- merged init: split Wi/Ws, transpose+split Wbil, leaves
__global__ void k_init(const float* __restrict__ seqt,
                       const float* __restrict__ Wi, const float* __restrict__ Ws,
                       const float* __restrict__ Wbil,
                       ushort_t* __restrict__ WiBh, ushort_t* __restrict__ WiBl,
                       ushort_t* __restrict__ WsBh, ushort_t* __restrict__ WsBl,
                       ushort_t* __restrict__ WbilTh, ushort_t* __restrict__ WbilTl,
                       float* __restrict__ cH, float* __restrict__ cC, float* __restrict__ cS,
                       ushort_t* __restrict__ cHbh, ushort_t* __restrict__ cHbl,
                       ushort_t* __restrict__ cCbh, ushort_t* __restrict__ cCbl){
  const int blk = blockIdx.x, t = threadIdx.x;
  if (blk < 10240){                       // Wi/Ws split (2*H5*H elems exactly)
    int i = blk*256 + t;
    const int n = H5*H;
    if (i < n) split_store(WiBh, WiBl, i, Wi[i]);
    else       split_store(WsBh, WsBl, i-n, Ws[i-n]);
  } else if (blk < 11264){                // Wbil transpose+split (1024 tiles)
    __shared__ float tile[32][33];
    int tb = blk - 10240;
    int tr = (tb>>5)*32, tc = (tb&31)*32;
    int tx = t & 31, ty = t >> 5;         // 32 x 8
    #pragma unroll
    for (int i=0;i<32;i+=8)
      tile[ty+i][tx] = Wbil[(size_t)(tr+ty+i)*H2 + tc+tx];
    __syncthreads();
    #pragma unroll
    for (int i=0;i<32;i+=8)
      split_store(WbilTh, WbilTl, (size_t)(tc+ty+i)*H2 + tr+tx, tile[tx][ty+i]);
  } else {                                // leaves (192 blocks)
    int tid = (blk-11264)*256 + t;
    if (tid < NB*NW*H){
      int b = tid/(NW*H); int r = tid%(NW*H); int i = r/H; int d = r%H;
      size_t idx = (size_t)(b*NCELL + i)*H + d;     // coff(0)==0
      float hv = seqt[(size_t)(b*NW+i)*H2 + d];
      float cv = seqt[(size_t)(b*NW+i)*H2 + H + d];
      cH[idx]=hv; cC[idx]=cv;
      split_store(cHbh,cHbl,idx,hv);
      split_store(cCbh,cCbl,idx,cv);
      if (d==0) cS[b*NCELL+i] = 0.f;
    }
  }
}

__device__ __forceinline__ void mfma3(f32x4& acc, bf16x8 ah, bf16x8 al,
                                      bf16x8 bh, bf16x8 bl){
  // split product; lo*lo (~2^-34 rel) dropped
  acc = __builtin_amdgcn_mfma_f32_16x16x32_bf16(ah, bh, acc, 0,0,0);
  acc = __builtin_amdgcn_mfma_f32_16x16x32_bf16(ah, bl, acc, 0,0,0);
  acc = __builtin_amdgcn_mfma_f32_16x16x32_bf16(al, bh, acc, 0,0,0);
}

// ---- MFMA projections, K-split across the block's 4 waves (r13 win).
// grid.x = 384 j-tiles (0-159: PI, 160-319: PS, 320-383: U), grid.y = m/16.
__global__ void __launch_bounds__(256)
k_projN(const ushort_t* __restrict__ WiBh, const ushort_t* __restrict__ WiBl,
        const ushort_t* __restrict__ WsBh, const ushort_t* __restrict__ WsBl,
        const ushort_t* __restrict__ WbilTh, const ushort_t* __restrict__ WbilTl,
        const float* __restrict__ bi, const float* __restrict__ bs,
        const ushort_t* __restrict__ cHbh, const ushort_t* __restrict__ cHbl,
        const ushort_t* __restrict__ cCbh, const ushort_t* __restrict__ cCbl,
        float* __restrict__ cPI, float* __restrict__ cPS, float* __restrict__ cU,
        int d, int P)
{
  __shared__ f32x4 red[4][64];
  const int t = threadIdx.x, wave = t>>6, lane = t&63;
  const int jt = blockIdx.x;
  const int m0 = blockIdx.y*16;
  const int Mtot = NB*P;
  const int nm = min(16, Mtot-m0);

  int kind, j0;
  if (jt < 160){ kind=0; j0 = jt*16; }
  else if (jt < 320){ kind=1; j0 = (jt-160)*16; }
  else { kind=2; j0 = (jt-320)*16; }

  const int r = lane & 15;   // A row (m) / B row (j) / D col
  const int q = lane >> 4;   // quad: k = q*8 + i

  int mg = m0 + (r < nm ? r : 0);
  const size_t arow = (size_t)((mg/P)*NCELL + coff(d) + mg%P)*H;

  f32x4 acc = {0.f,0.f,0.f,0.f};

  if (kind < 2){
    const ushort_t* bh_ = (kind==0 ? WiBh : WsBh) + (size_t)(j0+r)*H;
    const ushort_t* bl_ = (kind==0 ? WiBl : WsBl) + (size_t)(j0+r)*H;
    const int ks = wave*128 + q*8;          // this wave's K-quarter
    bf16x8 fah[4], fal[4], fbh[4], fbl[4];
    #pragma unroll
    for (int s=0;s<4;s++){
      const int ko = ks + s*32;
      fah[s] = *(const bf16x8*)(cHbh + arow + ko);
      fal[s] = *(const bf16x8*)(cHbl + arow + ko);
      fbh[s] = *(const bf16x8*)(bh_ + ko);
      fbl[s] = *(const bf16x8*)(bl_ + ko);
    }
    #pragma unroll
    for (int s=0;s<4;s++) mfma3(acc, fah[s], fal[s], fbh[s], fbl[s]);
  } else {
    // U: global k in [0,1024); waves 0,1 -> H chart, 2,3 -> C chart
    const ushort_t* bh_ = WbilTh + (size_t)(j0+r)*H2;
    const ushort_t* bl_ = WbilTl + (size_t)(j0+r)*H2;
    const ushort_t* ah_ = (wave<2 ? cHbh : cCbh) + arow;
    const ushort_t* al_ = (wave<2 ? cHbl : cCbl) + arow;
    const int kg0 = wave*256;               // global k base
    const int ka0 = kg0 & 511;              // chart k base
    #pragma unroll
    for (int gz=0; gz<2; gz++){             // 2 groups of 4 steps
      bf16x8 fah[4], fal[4], fbh[4], fbl[4];
      #pragma unroll
      for (int s=0;s<4;s++){
        const int so = (gz*4+s)*32 + q*8;
        fah[s] = *(const bf16x8*)(ah_ + ka0 + so);
        fal[s] = *(const bf16x8*)(al_ + ka0 + so);
        fbh[s] = *(const bf16x8*)(bh_ + kg0 + so);
        fbl[s] = *(const bf16x8*)(bl_ + kg0 + so);
      }
      #pragma unroll
      for (int s=0;s<4;s++) mfma3(acc, fah[s], fal[s], fbh[s], fbl[s]);
    }
  }

  red[wave][lane] = acc;
  __syncthreads();
  if (wave == 0){
    f32x4 s0 = red[0][lane], s1 = red[1][lane], s2 = red[2][lane], s3 = red[3][lane];
    f32x4 tot = (s0+s1) + (s2+s3);          // fixed order -> deterministic
    const int jo = j0 + r;
    float bias = 0.f;
    if (kind==0) bias = bi[jo] + ((jo>=H && jo<3*H)?1.f:0.f);   // ins_bias on [H,3H)
    else if (kind==1) bias = bs[jo];
    #pragma unroll
    for (int reg=0; reg<4; reg++){
      const int m = q*4 + reg;
      if (m < nm){
        const int mg2 = m0 + m;
        const size_t cell = (size_t)((mg2/P)*NCELL + coff(d) + mg2%P);
        const float v = tot[reg];
        if (kind==0)      cPI[cell*H5 + jo] = v + bias;
        else if (kind==1) cPS[cell*H5 + jo] = v + bias;
        else              cU [cell*H2 + jo] = v;
      }
    }
  }
}

// ---- combine diagonal L. r13 budget showed combine ~25us/dispatch = the
// phase-3 per-thread chain (L x 12 loads, MLP~1) on tiny tail grids. Fix by
// the two levers that worked on proj: grid x4 (128-dim slices; phase 1+2
// duplicated per slice -- bitwise identical so weights agree) and chain /2
// (t>>7 selects even/odd k; fixed-order LDS fold of the two partials).
__global__ void __launch_bounds__(256)
k_combine2(const float* __restrict__ cPI, const float* __restrict__ cPS,
           const float* __restrict__ cU,
           float* __restrict__ cH, float* __restrict__ cC, float* __restrict__ cS,
           ushort_t* __restrict__ cHbh, ushort_t* __restrict__ cHbl,
           ushort_t* __restrict__ cCbh, ushort_t* __restrict__ cCbl,
           int L, int P){
  const int t = threadIdx.x;
  const int b = blockIdx.x / P;
  const int left = blockIdx.x % P;
  const int dg = blockIdx.y;          // dim-group: dims [dg*128, dg*128+128)
  __shared__ float compat_s[32];
  __shared__ float wts_s[32];
  __shared__ float S_s;
  __shared__ float partH[128];
  __shared__ float partC[128];
  const int lane = t & 63;
  const int wv = t >> 6;
  // phase 1: compat_k = U[lcell].[H;C][rcell] + lS + rS (duplicated per dg)
  for (int k=wv; k<L; k+=4){
    int lc = b*NCELL + coff(k) + left;
    int rc = b*NCELL + coff(L-1-k) + left+k+1;
    const float2* U2l = (const float2*)(cU + (size_t)lc*H2);
    const float2* U2h = (const float2*)(cU + (size_t)lc*H2 + H);
    const float2* Hr2 = (const float2*)(cH + (size_t)rc*H);
    const float2* Cr2 = (const float2*)(cC + (size_t)rc*H);
    float p = 0.f;
    #pragma unroll
    for (int it=0; it<4; it++){
      int i = lane + it*64;                 // float2 index 0..255
      float2 u0 = U2l[i], u1 = U2h[i], hh = Hr2[i], cc = Cr2[i];
      p += u0.x*hh.x + u0.y*hh.y + u1.x*cc.x + u1.y*cc.y;
    }
    #pragma unroll
    for (int off=32; off>0; off>>=1) p += __shfl_down(p, off);
    if (lane==0) compat_s[k] = p + cS[lc] + cS[rc];
  }
  __syncthreads();
  // phase 2: softmax over k (L<=23, serial on thread 0)
  if (t==0){
    float mx = -1e30f;
    for (int k=0;k<L;k++) mx = fmaxf(mx, compat_s[k]);
    float den = 0.f;
    for (int k=0;k<L;k++){ float e = __expf(compat_s[k]-mx); wts_s[k]=e; den+=e; }
    float inv = 1.f/den, S = 0.f;
    for (int k=0;k<L;k++){ wts_s[k]*=inv; S += wts_s[k]*compat_s[k]; }
    S_s = S;
  }
  __syncthreads();
  // phase 3: thread owns 1 dim; t>>7 selects even/odd k subset
  const int dloc = t & 127;
  const int dim = dg*128 + dloc;
  const int kpar = t >> 7;
  float aH = 0.f, aC = 0.f;
  for (int k=kpar; k<L; k+=2){
    float wk = wts_s[k];
    int lc = b*NCELL + coff(k) + left;
    int rc = b*NCELL + coff(L-1-k) + left+k+1;
    const float* PI = cPI + (size_t)lc*H5;
    const float* PS = cPS + (size_t)rc*H5;
    float p0 = PI[dim]     + PS[dim];
    float p1 = PI[H+dim]   + PS[H+dim];
    float p2 = PI[2*H+dim] + PS[2*H+dim];
    float p3 = PI[3*H+dim] + PS[3*H+dim];
    float p4 = PI[4*H+dim] + PS[4*H+dim];
    float lcv = cC[(size_t)lc*H + dim];
    float rcv = cC[(size_t)rc*H + dim];
    float mem = sigm(p1)*lcv + sigm(p2)*rcv + sigm(p0)*ftanh(p3);
    float h = sigm(p4)*ftanh(mem);
    aH += wk*h; aC += wk*mem;
  }
  if (kpar==1){ partH[dloc]=aH; partC[dloc]=aC; }
  __syncthreads();
  if (kpar==0){
    aH += partH[dloc];                 // fixed order: even + odd
    aC += partC[dloc];
    size_t nc = (size_t)(b*NCELL + coff(L) + left);
    cH[nc*H + dim] = aH;
    cC[nc*H + dim] = aC;
    split_store(cHbh,cHbl, nc*H + dim, aH);
    split_store(cCbh,cCbl, nc*H + dim, aC);
    if (t==0 && dg==0) cS[nc] = S_s;
  }
}

// ---- root output: concat(H, C) of cell (0, n-1)
__global__ void k_out(const float* __restrict__ cH, const float* __restrict__ cC,
                      float* __restrict__ out){
  int tid = blockIdx.x*256+threadIdx.x;
  if (tid >= NB*H2) return;
  int b = tid>>10, d = tid&1023;
  int cell = b*NCELL + 299;   // coff(23)+0
  out[tid] = (d<H) ? cH[(size_t)cell*H + d] : cC[(size_t)cell*H + (d-H)];
}

extern "C" void kernel_launch(void* const* d_in, const int* in_sizes, int n_in,
                              void* d_out, int out_size, void* d_ws, size_t ws_size,
                              hipStream_t stream){
  const float* seqt = (const float*)d_in[0];
  const float* Wi   = (const float*)d_in[1];
  const float* bi   = (const float*)d_in[2];
  const float* Ws   = (const float*)d_in[3];
  const float* bs   = (const float*)d_in[4];
  const float* Wbil = (const float*)d_in[5];
  float* out = (float*)d_out;

  float* p = (ws_size >= NEED_BYTES && g_buf == nullptr) ? (float*)d_ws : g_buf;
  float* cH  = p; p += (size_t)NB*NCELL*H;
  float* cC  = p; p += (size_t)NB*NCELL*H;
  float* cS  = p; p += (size_t)NB*NCELL;
  float* cPI = p; p += (size_t)NB*NCELL*H5;
  float* cPS = p; p += (size_t)NB*NCELL*H5;
  float* cU  = p; p += (size_t)NB*NCELL*H2;
  ushort_t* u = (ushort_t*)p;
  ushort_t* WiBh   = u; u += (size_t)H5*H;
  ushort_t* WiBl   = u; u += (size_t)H5*H;
  ushort_t* WsBh   = u; u += (size_t)H5*H;
  ushort_t* WsBl   = u; u += (size_t)H5*H;
  ushort_t* WbilTh = u; u += (size_t)H2*H2;
  ushort_t* WbilTl = u; u += (size_t)H2*H2;
  ushort_t* cHbh   = u; u += (size_t)NB*NCELL*H;
  ushort_t* cHbl   = u; u += (size_t)NB*NCELL*H;
  ushort_t* cCbh   = u; u += (size_t)NB*NCELL*H;
  ushort_t* cCbl   = u; u += (size_t)NB*NCELL*H;

  k_init<<<11456, 256, 0, stream>>>(seqt, Wi, Ws, Wbil,
      WiBh, WiBl, WsBh, WsBl, WbilTh, WbilTl,
      cH, cC, cS, cHbh, cHbl, cCbh, cCbl);

  k_projN<<<dim3(384, (NB*NW+15)/16), 256, 0, stream>>>(
      WiBh, WiBl, WsBh, WsBl, WbilTh, WbilTl, bi, bs,
      cHbh, cHbl, cCbh, cCbl, cPI, cPS, cU, 0, NW);
  for (int L=1; L<NW; L++){
    int P = NW - L;
    k_combine2<<<dim3(NB*P, 4), 256, 0, stream>>>(cPI, cPS, cU, cH, cC, cS,
                                                  cHbh, cHbl, cCbh, cCbl, L, P);
    if (L < NW-1)
      k_projN<<<dim3(384, (NB*P+15)/16), 256, 0, stream>>>(
          WiBh, WiBl, WsBh, WsBl, WbilTh, WbilTl, bi, bs,
          cHbh, cHbl, cCbh, cCbl, cPI, cPS, cU, L, P);
  }
  k_out<<<16, 256, 0, stream>>>(cH, cC, out);
}

// Round 15
// 625.860 us; speedup vs baseline: 5.8779x; 1.1037x over previous
//
#include <hip/hip_runtime.h>
#include <math.h>

#define NB 4
#define NW 24
#define H 512
#define H2 1024
#define H5 2560
#define NCELL 300   // n*(n+1)/2 valid cells per batch
#define NEED_BYTES ((size_t)72<<20)

// Private fallback workspace: allocated ONCE at library load (outside
// kernel_launch, so graph capture never sees the hipMalloc). d_ws proved too
// small in round 1 (44.9MB layout corrupted adjacent harness allocations).
static float* g_buf = nullptr;
__attribute__((constructor)) static void dio_alloc_ws(){
  (void)hipMalloc((void**)&g_buf, NEED_BYTES);
}

typedef __attribute__((ext_vector_type(8))) short bf16x8;   // 8 bf16 (4 VGPRs)
typedef __attribute__((ext_vector_type(4))) float f32x4;
typedef unsigned short ushort_t;

__device__ __forceinline__ int coff(int l){ return l*NW - (l*(l-1))/2; }
__device__ __forceinline__ float sigm(float x){ return 1.f/(1.f+__expf(-x)); }
__device__ __forceinline__ float ftanh(float x){ return 1.f - 2.f/(__expf(2.f*x)+1.f); }

__device__ __forceinline__ ushort_t f2b(float x){  // fp32 -> bf16 RNE
  unsigned int u = __float_as_uint(x);
  u += 0x7FFF + ((u>>16)&1);
  return (ushort_t)(u>>16);
}
__device__ __forceinline__ float b2f(ushort_t h){
  return __uint_as_float(((unsigned int)h)<<16);
}
// split-bf16: x ~= hi + lo with effective ~2^-17 relative error
__device__ __forceinline__ void split_store(ushort_t* __restrict__ ph,
                                            ushort_t* __restrict__ pl,
                                            size_t idx, float x){
  ushort_t h = f2b(x);
  ph[idx] = h;
  pl[idx] = f2b(x - b2f(h));
}

// full-wave dot: compat(lc,rc) = U[lc].[H(rc);C(rc)] + S[lc] + S[rc]
__device__ __forceinline__ float compat_dot(const float* __restrict__ cU,
                                            const float* __restrict__ cH,
                                            const float* __restrict__ cC,
                                            const float* __restrict__ cS,
                                            int lc, int rc, int lane){
  const float4* U4  = (const float4*)(cU + (size_t)lc*H2);
  const float4* Hr4 = (const float4*)(cH + (size_t)rc*H);
  const float4* Cr4 = (const float4*)(cC + (size_t)rc*H);
  float p = 0.f;
  #pragma unroll
  for (int it=0; it<2; it++){
    float4 u = U4[lane + 64*it], h = Hr4[lane + 64*it];
    p += u.x*h.x + u.y*h.y + u.z*h.z + u.w*h.w;
  }
  #pragma unroll
  for (int it=0; it<2; it++){
    float4 u = U4[128 + lane + 64*it], c = Cr4[lane + 64*it];
    p += u.x*c.x + u.y*c.y + u.z*c.z + u.w*c.w;
  }
  #pragma unroll
  for (int off=32; off>0; off>>=1) p += __shfl_down(p, off);
  return p + cS[lc] + cS[rc];
}

// ---- merged init: split Wi/Ws, transpose+split Wbil, leaves
__global__ void k_init(const float* __restrict__ seqt,
                       const float* __restrict__ Wi, const float* __restrict__ Ws,
                       const float* __restrict__ Wbil,
                       ushort_t* __restrict__ WiBh, ushort_t* __restrict__ WiBl,
                       ushort_t* __restrict__ WsBh, ushort_t* __restrict__ WsBl,
                       ushort_t* __restrict__ WbilTh, ushort_t* __restrict__ WbilTl,
                       float* __restrict__ cH, float* __restrict__ cC, float* __restrict__ cS,
                       ushort_t* __restrict__ cHbh, ushort_t* __restrict__ cHbl,
                       ushort_t* __restrict__ cCbh, ushort_t* __restrict__ cCbl){
  const int blk = blockIdx.x, t = threadIdx.x;
  if (blk < 10240){                       // Wi/Ws split (2*H5*H elems exactly)
    int i = blk*256 + t;
    const int n = H5*H;
    if (i < n) split_store(WiBh, WiBl, i, Wi[i]);
    else       split_store(WsBh, WsBl, i-n, Ws[i-n]);
  } else if (blk < 11264){                // Wbil transpose+split (1024 tiles)
    __shared__ float tile[32][33];
    int tb = blk - 10240;
    int tr = (tb>>5)*32, tc = (tb&31)*32;
    int tx = t & 31, ty = t >> 5;         // 32 x 8
    #pragma unroll
    for (int i=0;i<32;i+=8)
      tile[ty+i][tx] = Wbil[(size_t)(tr+ty+i)*H2 + tc+tx];
    __syncthreads();
    #pragma unroll
    for (int i=0;i<32;i+=8)
      split_store(WbilTh, WbilTl, (size_t)(tc+ty+i)*H2 + tr+tx, tile[tx][ty+i]);
  } else {                                // leaves (192 blocks)
    int tid = (blk-11264)*256 + t;
    if (tid < NB*NW*H){
      int b = tid/(NW*H); int r = tid%(NW*H); int i = r/H; int d = r%H;
      size_t idx = (size_t)(b*NCELL + i)*H + d;     // coff(0)==0
      float hv = seqt[(size_t)(b*NW+i)*H2 + d];
      float cv = seqt[(size_t)(b*NW+i)*H2 + H + d];
      cH[idx]=hv; cC[idx]=cv;
      split_store(cHbh,cHbl,idx,hv);
      split_store(cCbh,cCbl,idx,cv);
      if (d==0) cS[b*NCELL+i] = 0.f;
    }
  }
}

__device__ __forceinline__ void mfma3(f32x4& acc, bf16x8 ah, bf16x8 al,
                                      bf16x8 bh, bf16x8 bl){
  // split product; lo*lo (~2^-34 rel) dropped
  acc = __builtin_amdgcn_mfma_f32_16x16x32_bf16(ah, bh, acc, 0,0,0);
  acc = __builtin_amdgcn_mfma_f32_16x16x32_bf16(ah, bl, acc, 0,0,0);
  acc = __builtin_amdgcn_mfma_f32_16x16x32_bf16(al, bh, acc, 0,0,0);
}

// ---- MFMA projections, K-split across 8 waves (r13's 4-way chain halved:
// PI/PS = 8 serial loads/wave, U = 16).
// grid.x = 384 j-tiles (0-159: PI, 160-319: PS, 320-383: U), grid.y = m/16.
__global__ void __launch_bounds__(512)
k_projN(const ushort_t* __restrict__ WiBh, const ushort_t* __restrict__ WiBl,
        const ushort_t* __restrict__ WsBh, const ushort_t* __restrict__ WsBl,
        const ushort_t* __restrict__ WbilTh, const ushort_t* __restrict__ WbilTl,
        const float* __restrict__ bi, const float* __restrict__ bs,
        const ushort_t* __restrict__ cHbh, const ushort_t* __restrict__ cHbl,
        const ushort_t* __restrict__ cCbh, const ushort_t* __restrict__ cCbl,
        float* __restrict__ cPI, float* __restrict__ cPS, float* __restrict__ cU,
        int d, int P)
{
  __shared__ f32x4 red[8][64];
  const int t = threadIdx.x, wave = t>>6, lane = t&63;
  const int jt = blockIdx.x;
  const int m0 = blockIdx.y*16;
  const int Mtot = NB*P;
  const int nm = min(16, Mtot-m0);

  int kind, j0;
  if (jt < 160){ kind=0; j0 = jt*16; }
  else if (jt < 320){ kind=1; j0 = (jt-160)*16; }
  else { kind=2; j0 = (jt-320)*16; }

  const int r = lane & 15;   // A row (m) / B row (j) / D col
  const int q = lane >> 4;   // quad: k = q*8 + i

  int mg = m0 + (r < nm ? r : 0);
  const size_t arow = (size_t)((mg/P)*NCELL + coff(d) + mg%P)*H;

  f32x4 acc = {0.f,0.f,0.f,0.f};

  if (kind < 2){
    const ushort_t* bh_ = (kind==0 ? WiBh : WsBh) + (size_t)(j0+r)*H;
    const ushort_t* bl_ = (kind==0 ? WiBl : WsBl) + (size_t)(j0+r)*H;
    const int ks = wave*64 + q*8;           // this wave's K/8 slice
    bf16x8 fah[2], fal[2], fbh[2], fbl[2];
    #pragma unroll
    for (int s=0;s<2;s++){
      const int ko = ks + s*32;
      fah[s] = *(const bf16x8*)(cHbh + arow + ko);
      fal[s] = *(const bf16x8*)(cHbl + arow + ko);
      fbh[s] = *(const bf16x8*)(bh_ + ko);
      fbl[s] = *(const bf16x8*)(bl_ + ko);
    }
    #pragma unroll
    for (int s=0;s<2;s++) mfma3(acc, fah[s], fal[s], fbh[s], fbl[s]);
  } else {
    // U: global k in [0,1024); waves 0-3 -> H chart, 4-7 -> C chart
    const ushort_t* bh_ = WbilTh + (size_t)(j0+r)*H2;
    const ushort_t* bl_ = WbilTl + (size_t)(j0+r)*H2;
    const ushort_t* ah_ = (wave<4 ? cHbh : cCbh) + arow;
    const ushort_t* al_ = (wave<4 ? cHbl : cCbl) + arow;
    const int kg0 = wave*128;               // global k base
    const int ka0 = kg0 & 511;              // chart k base
    bf16x8 fah[4], fal[4], fbh[4], fbl[4];
    #pragma unroll
    for (int s=0;s<4;s++){
      const int so = s*32 + q*8;
      fah[s] = *(const bf16x8*)(ah_ + ka0 + so);
      fal[s] = *(const bf16x8*)(al_ + ka0 + so);
      fbh[s] = *(const bf16x8*)(bh_ + kg0 + so);
      fbl[s] = *(const bf16x8*)(bl_ + kg0 + so);
    }
    #pragma unroll
    for (int s=0;s<4;s++) mfma3(acc, fah[s], fal[s], fbh[s], fbl[s]);
  }

  red[wave][lane] = acc;
  __syncthreads();
  if (wave == 0){
    f32x4 s0=red[0][lane], s1=red[1][lane], s2=red[2][lane], s3=red[3][lane];
    f32x4 s4=red[4][lane], s5=red[5][lane], s6=red[6][lane], s7=red[7][lane];
    f32x4 tot = ((s0+s1)+(s2+s3)) + ((s4+s5)+(s6+s7));   // fixed order
    const int jo = j0 + r;
    float bias = 0.f;
    if (kind==0) bias = bi[jo] + ((jo>=H && jo<3*H)?1.f:0.f);   // ins_bias on [H,3H)
    else if (kind==1) bias = bs[jo];
    #pragma unroll
    for (int reg=0; reg<4; reg++){
      const int m = q*4 + reg;
      if (m < nm){
        const int mg2 = m0 + m;
        const size_t cell = (size_t)((mg2/P)*NCELL + coff(d) + mg2%P);
        const float v = tot[reg];
        if (kind==0)      cPI[cell*H5 + jo] = v + bias;
        else if (kind==1) cPS[cell*H5 + jo] = v + bias;
        else              cU [cell*H2 + jo] = v;
      }
    }
  }
}

// ---- combine diagonal L. Phase 1 hoisted: compat terms k in [1,L-2] were
// precomputed by the PREVIOUS combine dispatch's writer blocks (they touch
// only diag <= L-2 data, final then); only boundary terms k=0 and k=L-1
// (touching diag L-1) are computed inline. This dispatch's extra blocks
// precompute compat terms k in [1,L-1] for diag L+1 into the ping-pong
// write buffer (reads diag <= L-1 only -> no race with phase writes to
// diag L). Phase 3: 32 dims x 8-way k-split.
// grid.x = NB*P*16 phase blocks + ceil(NB*(P-1)*(L-1)/4) writer blocks.
__global__ void __launch_bounds__(256)
k_combine3(const float* __restrict__ cPI, const float* __restrict__ cPS,
           const float* __restrict__ cU,
           float* __restrict__ cH, float* __restrict__ cC, float* __restrict__ cS,
           ushort_t* __restrict__ cHbh, ushort_t* __restrict__ cHbl,
           ushort_t* __restrict__ cCbh, ushort_t* __restrict__ cCbl,
           const float* __restrict__ compatR, float* __restrict__ compatW,
           int L, int P){
  const int t = threadIdx.x;
  const int lane = t & 63;
  const int wave = t >> 6;
  const int nphase = NB*P*16;
  const int blk = blockIdx.x;

  if (blk >= nphase){
    // writer: one wave per (cell of diag L+1, split k in [1,L-1])
    const int P1 = P-1;
    const int nterm = L-1;
    int tid = (blk-nphase)*4 + wave;
    if (P1 > 0 && nterm > 0 && tid < NB*P1*nterm){
      int cell1 = tid / nterm;
      int k = 1 + tid % nterm;
      int b = cell1 / P1, left = cell1 % P1;
      // diag L+1 span (left): lcell=(left,k), rcell=(left+k+1, L-k)
      int lc = b*NCELL + coff(k) + left;
      int rc = b*NCELL + coff(L-k) + left+k+1;
      float v = compat_dot(cU, cH, cC, cS, lc, rc, lane);
      if (lane==0) compatW[(b*NW + left)*NW + k] = v;
    }
    return;
  }

  const int cellid = blk >> 4;
  const int dg = blk & 15;            // dim-group: dims [dg*32, dg*32+32)
  const int b = cellid / P;
  const int left = cellid % P;
  __shared__ float compat_s[32];
  __shared__ float wts_s[32];
  __shared__ float S_s;
  __shared__ float partH[8][32];
  __shared__ float partC[8][32];

  // phase 1: boundary terms inline (k=0 by wave 0, k=L-1 by wave 1);
  // interior terms from the precomputed buffer.
  if (wave == 0){
    int lc = b*NCELL + left;                       // (left,0) leaf
    int rc = b*NCELL + coff(L-1) + left+1;
    float v = compat_dot(cU, cH, cC, cS, lc, rc, lane);
    if (lane==0) compat_s[0] = v;
  } else if (wave == 1 && L >= 2){
    int lc = b*NCELL + coff(L-1) + left;
    int rc = b*NCELL + left+L;                     // (left+L,0) leaf
    float v = compat_dot(cU, cH, cC, cS, lc, rc, lane);
    if (lane==0) compat_s[L-1] = v;
  }
  if (t >= 1 && t <= L-2) compat_s[t] = compatR[(b*NW + left)*NW + t];
  __syncthreads();
  // phase 2: softmax over k (L<=23, serial on thread 0)
  if (t==0){
    float mx = -1e30f;
    for (int k=0;k<L;k++) mx = fmaxf(mx, compat_s[k]);
    float den = 0.f;
    for (int k=0;k<L;k++){ float e = __expf(compat_s[k]-mx); wts_s[k]=e; den+=e; }
    float inv = 1.f/den, S = 0.f;
    for (int k=0;k<L;k++){ wts_s[k]*=inv; S += wts_s[k]*compat_s[k]; }
    S_s = S;
  }
  __syncthreads();
  // phase 3: thread owns 1 dim; t>>5 selects k-residue (8-way split)
  const int dloc = t & 31;
  const int dim = dg*32 + dloc;
  const int kpar = t >> 5;
  float aH = 0.f, aC = 0.f;
  for (int k=kpar; k<L; k+=8){
    float wk = wts_s[k];
    int lc = b*NCELL + coff(k) + left;
    int rc = b*NCELL + coff(L-1-k) + left+k+1;
    const float* PI = cPI + (size_t)lc*H5;
    const float* PS = cPS + (size_t)rc*H5;
    float p0 = PI[dim]     + PS[dim];
    float p1 = PI[H+dim]   + PS[H+dim];
    float p2 = PI[2*H+dim] + PS[2*H+dim];
    float p3 = PI[3*H+dim] + PS[3*H+dim];
    float p4 = PI[4*H+dim] + PS[4*H+dim];
    float lcv = cC[(size_t)lc*H + dim];
    float rcv = cC[(size_t)rc*H + dim];
    float mem = sigm(p1)*lcv + sigm(p2)*rcv + sigm(p0)*ftanh(p3);
    float h = sigm(p4)*ftanh(mem);
    aH += wk*h; aC += wk*mem;
  }
  if (kpar > 0){ partH[kpar][dloc]=aH; partC[kpar][dloc]=aC; }
  __syncthreads();
  if (kpar == 0){
    #pragma unroll
    for (int q=1;q<8;q++){ aH += partH[q][dloc]; aC += partC[q][dloc]; }
    size_t nc = (size_t)(b*NCELL + coff(L) + left);
    cH[nc*H + dim] = aH;
    cC[nc*H + dim] = aC;
    split_store(cHbh,cHbl, nc*H + dim, aH);
    split_store(cCbh,cCbl, nc*H + dim, aC);
    if (t==0 && dg==0) cS[nc] = S_s;
  }
}

// ---- root output: concat(H, C) of cell (0, n-1)
__global__ void k_out(const float* __restrict__ cH, const float* __restrict__ cC,
                      float* __restrict__ out){
  int tid = blockIdx.x*256+threadIdx.x;
  if (tid >= NB*H2) return;
  int b = tid>>10, d = tid&1023;
  int cell = b*NCELL + 299;   // coff(23)+0
  out[tid] = (d<H) ? cH[(size_t)cell*H + d] : cC[(size_t)cell*H + (d-H)];
}

extern "C" void kernel_launch(void* const* d_in, const int* in_sizes, int n_in,
                              void* d_out, int out_size, void* d_ws, size_t ws_size,
                              hipStream_t stream){
  const float* seqt = (const float*)d_in[0];
  const float* Wi   = (const float*)d_in[1];
  const float* bi   = (const float*)d_in[2];
  const float* Ws   = (const float*)d_in[3];
  const float* bs   = (const float*)d_in[4];
  const float* Wbil = (const float*)d_in[5];
  float* out = (float*)d_out;

  float* p = (ws_size >= NEED_BYTES && g_buf == nullptr) ? (float*)d_ws : g_buf;
  float* cH  = p; p += (size_t)NB*NCELL*H;
  float* cC  = p; p += (size_t)NB*NCELL*H;
  float* cS  = p; p += (size_t)NB*NCELL;
  float* cPI = p; p += (size_t)NB*NCELL*H5;
  float* cPS = p; p += (size_t)NB*NCELL*H5;
  float* cU  = p; p += (size_t)NB*NCELL*H2;
  float* compatA = p; p += (size_t)NB*NW*NW;
  float* compatB = p; p += (size_t)NB*NW*NW;
  ushort_t* u = (ushort_t*)p;
  ushort_t* WiBh   = u; u += (size_t)H5*H;
  ushort_t* WiBl   = u; u += (size_t)H5*H;
  ushort_t* WsBh   = u; u += (size_t)H5*H;
  ushort_t* WsBl   = u; u += (size_t)H5*H;
  ushort_t* WbilTh = u; u += (size_t)H2*H2;
  ushort_t* WbilTl = u; u += (size_t)H2*H2;
  ushort_t* cHbh   = u; u += (size_t)NB*NCELL*H;
  ushort_t* cHbl   = u; u += (size_t)NB*NCELL*H;
  ushort_t* cCbh   = u; u += (size_t)NB*NCELL*H;
  ushort_t* cCbl   = u; u += (size_t)NB*NCELL*H;

  k_init<<<11456, 256, 0, stream>>>(seqt, Wi, Ws, Wbil,
      WiBh, WiBl, WsBh, WsBl, WbilTh, WbilTl,
      cH, cC, cS, cHbh, cHbl, cCbh, cCbl);

  k_projN<<<dim3(384, (NB*NW+15)/16), 512, 0, stream>>>(
      WiBh, WiBl, WsBh, WsBl, WbilTh, WbilTl, bi, bs,
      cHbh, cHbl, cCbh, cCbl, cPI, cPS, cU, 0, NW);
  for (int L=1; L<NW; L++){
    int P = NW - L;
    // writer blocks precompute compat interior terms for diagonal L+1
    int P1 = P-1, nterm = L-1;
    int wblk = (P1>0 && nterm>0) ? (NB*P1*nterm + 3)/4 : 0;
    float* bufR = (L&1) ? compatA : compatB;
    float* bufW = (L&1) ? compatB : compatA;
    k_combine3<<<NB*P*16 + wblk, 256, 0, stream>>>(
        cPI, cPS, cU, cH, cC, cS, cHbh, cHbl, cCbh, cCbl,
        bufR, bufW, L, P);
    if (L < NW-1)
      k_projN<<<dim3(384, (NB*P+15)/16), 512, 0, stream>>>(
          WiBh, WiBl, WsBh, WsBl, WbilTh, WbilTl, bi, bs,
          cHbh, cHbl, cCbh, cCbl, cPI, cPS, cU, L, P);
  }
  k_out<<<16, 256, 0, stream>>>(cH, cC, out);
}